// Round 1
// baseline (1988.253 us; speedup 1.0000x reference)
//
#include <hip/hip_runtime.h>
#include <math.h>

#define TWO_PI 6.283185307179586f

// ---------------------------------------------------------------------------
// In-LDS 4096-point radix-2 DIT FFT (input already bit-reversed in LDS).
// sgn = -1 forward, +1 inverse. 256 threads, 8 butterflies/thread/stage.
// ---------------------------------------------------------------------------
__device__ __forceinline__ void fft4096(float* lre, float* lim, float sgn) {
    const int tid = threadIdx.x;
    for (int s = 1; s <= 12; ++s) {
        const int half = 1 << (s - 1);
        const float fac = sgn * TWO_PI / (float)(half << 1);
        __syncthreads();
        for (int idx = tid; idx < 2048; idx += 256) {
            const int j    = idx & (half - 1);
            const int base = ((idx >> (s - 1)) << s) + j;
            const int pair = base + half;
            float si, co;
            sincosf((float)j * fac, &si, &co);
            const float ur = lre[base], ui = lim[base];
            const float vr = lre[pair], vi = lim[pair];
            const float tr = vr * co - vi * si;
            const float ti = vr * si + vi * co;
            lre[base] = ur + tr;
            lim[base] = ui + ti;
            lre[pair] = ur - tr;
            lim[pair] = ui - ti;
        }
    }
    __syncthreads();
}

// K1: forward FFT along N for one (batch, channel) column. x real input.
extern "C" __global__ void __launch_bounds__(256)
fft_n_fwd(const float* __restrict__ x, float* __restrict__ pre, float* __restrict__ pim) {
    __shared__ float lre[4096];
    __shared__ float lim[4096];
    const int col = blockIdx.x;                       // b*512 + c
    const size_t base = (size_t)(col >> 9) * (4096ull * 512ull) + (size_t)(col & 511);
    for (int n = threadIdx.x; n < 4096; n += 256) {
        const float v = x[base + (size_t)n * 512];
        const int r = __brev((unsigned)n) >> 20;
        lre[r] = v;
        lim[r] = 0.0f;
    }
    fft4096(lre, lim, -1.0f);
    for (int n = threadIdx.x; n < 4096; n += 256) {
        pre[base + (size_t)n * 512] = lre[n];
        pim[base + (size_t)n * 512] = lim[n];
    }
}

// K6: inverse FFT along N; writes REAL part only (into pre == d_out).
extern "C" __global__ void __launch_bounds__(256)
fft_n_inv(float* __restrict__ pre, const float* __restrict__ pim) {
    __shared__ float lre[4096];
    __shared__ float lim[4096];
    const int col = blockIdx.x;
    const size_t base = (size_t)(col >> 9) * (4096ull * 512ull) + (size_t)(col & 511);
    for (int n = threadIdx.x; n < 4096; n += 256) {
        const int r = __brev((unsigned)n) >> 20;
        lre[r] = pre[base + (size_t)n * 512];
        lim[r] = pim[base + (size_t)n * 512];
    }
    fft4096(lre, lim, +1.0f);
    for (int n = threadIdx.x; n < 4096; n += 256) {
        pre[base + (size_t)n * 512] = lre[n];
    }
}

// K2: forward 4-point DFT across blocks, in place, with ortho scale 1/128.
extern "C" __global__ void __launch_bounds__(256)
fft4_fwd(float* __restrict__ re, float* __restrict__ im) {
    const size_t g = (size_t)blockIdx.x * 256 + threadIdx.x;   // < 8*4096*128
    const size_t d = g & 127;
    const size_t rown = g >> 7;                                 // b*4096 + n
    const size_t a0 = rown * 512 + d;
    const float r0 = re[a0], r1 = re[a0 + 128], r2 = re[a0 + 256], r3 = re[a0 + 384];
    const float m0 = im[a0], m1 = im[a0 + 128], m2 = im[a0 + 256], m3 = im[a0 + 384];
    const float s = 1.0f / 128.0f;
    re[a0]       = (r0 + r1 + r2 + r3) * s;  im[a0]       = (m0 + m1 + m2 + m3) * s;
    re[a0 + 128] = (r0 + m1 - r2 - m3) * s;  im[a0 + 128] = (m0 - r1 - m2 + r3) * s;
    re[a0 + 256] = (r0 - r1 + r2 - r3) * s;  im[a0 + 256] = (m0 - m1 + m2 - m3) * s;
    re[a0 + 384] = (r0 - m1 - r2 + m3) * s;  im[a0 + 384] = (m0 + r1 - m2 - r3) * s;
}

// K5: inverse 4-point DFT across blocks, in place, with ortho scale 1/128.
extern "C" __global__ void __launch_bounds__(256)
fft4_inv(float* __restrict__ re, float* __restrict__ im) {
    const size_t g = (size_t)blockIdx.x * 256 + threadIdx.x;
    const size_t d = g & 127;
    const size_t rown = g >> 7;
    const size_t a0 = rown * 512 + d;
    const float r0 = re[a0], r1 = re[a0 + 128], r2 = re[a0 + 256], r3 = re[a0 + 384];
    const float m0 = im[a0], m1 = im[a0 + 128], m2 = im[a0 + 256], m3 = im[a0 + 384];
    const float s = 1.0f / 128.0f;
    re[a0]       = (r0 + r1 + r2 + r3) * s;  im[a0]       = (m0 + m1 + m2 + m3) * s;
    re[a0 + 128] = (r0 - m1 - r2 + m3) * s;  im[a0 + 128] = (m0 + r1 - m2 - r3) * s;
    re[a0 + 256] = (r0 - r1 + r2 - r3) * s;  im[a0 + 256] = (m0 - m1 + m2 - m3) * s;
    re[a0 + 384] = (r0 + m1 - r2 - m3) * s;  im[a0 + 384] = (m0 - r1 - m2 + r3) * s;
}

// K3/K4: per-block complex 128->128 GEMM over 32-token row tiles, in place.
// LAYER==1: +bias, relu. LAYER==2: +bias, softshrink(0.01).
template<int LAYER>
__global__ void __launch_bounds__(256)
mlp_layer(float* __restrict__ re, float* __restrict__ im,
          const float* __restrict__ w, const float* __restrict__ bias) {
    __shared__ float Ar[32][128];
    __shared__ float Ai[32][128];
    const int blk = blockIdx.y;
    const size_t addrBase = (size_t)blockIdx.x * 32 * 512 + (size_t)blk * 128;

    for (int i = threadIdx.x; i < 32 * 128; i += 256) {
        const int rr = i >> 7, dd = i & 127;
        const size_t a = addrBase + (size_t)rr * 512 + dd;
        Ar[rr][dd] = re[a];
        Ai[rr][dd] = im[a];
    }
    __syncthreads();

    const int k  = threadIdx.x & 127;
    const int rg = (threadIdx.x >> 7) << 4;   // 0 or 16
    const float* W0 = w + (size_t)blk * 16384 + k;           // w[0][blk][d][k]
    const float* W1 = w + 65536 + (size_t)blk * 16384 + k;   // w[1][blk][d][k]

    float accr[16], acci[16];
#pragma unroll
    for (int j = 0; j < 16; ++j) { accr[j] = 0.0f; acci[j] = 0.0f; }

#pragma unroll 4
    for (int d = 0; d < 128; ++d) {
        const float w0  = W0[(size_t)d * 128];
        const float w1v = W1[(size_t)d * 128];
#pragma unroll
        for (int j = 0; j < 16; ++j) {
            const float ar = Ar[rg + j][d];
            const float ai = Ai[rg + j][d];
            accr[j] += ar * w0 - ai * w1v;
            acci[j] += ar * w1v + ai * w0;
        }
    }

    const float br = bias[blk * 128 + k];
    const float bi = bias[512 + blk * 128 + k];
#pragma unroll
    for (int j = 0; j < 16; ++j) {
        float vr = accr[j] + br;
        float vi = acci[j] + bi;
        if (LAYER == 1) {
            vr = fmaxf(vr, 0.0f);
            vi = fmaxf(vi, 0.0f);
        } else {
            vr = (vr > 0.01f) ? vr - 0.01f : ((vr < -0.01f) ? vr + 0.01f : 0.0f);
            vi = (vi > 0.01f) ? vi - 0.01f : ((vi < -0.01f) ? vi + 0.01f : 0.0f);
        }
        const size_t a = addrBase + (size_t)(rg + j) * 512 + k;
        re[a] = vr;
        im[a] = vi;
    }
}

extern "C" void kernel_launch(void* const* d_in, const int* in_sizes, int n_in,
                              void* d_out, int out_size, void* d_ws, size_t ws_size,
                              hipStream_t stream) {
    const float* x  = (const float*)d_in[0];
    const float* w1 = (const float*)d_in[1];
    const float* w2 = (const float*)d_in[2];
    const float* b1 = (const float*)d_in[3];
    const float* b2 = (const float*)d_in[4];

    float* pre = (float*)d_out;   // real plane; ends as the final output
    float* pim = (float*)d_ws;    // imag plane (64 MiB of workspace)

    // forward FFT2 (ortho): length-4096 FFT per column, then 4-point across blocks
    fft_n_fwd<<<4096, 256, 0, stream>>>(x, pre, pim);
    fft4_fwd<<<16384, 256, 0, stream>>>(pre, pim);

    // block-diagonal complex MLP, in place
    mlp_layer<1><<<dim3(1024, 4), 256, 0, stream>>>(pre, pim, w1, b1);
    mlp_layer<2><<<dim3(1024, 4), 256, 0, stream>>>(pre, pim, w2, b2);

    // inverse FFT2 (ortho): 4-point across blocks, then length-4096 per column
    fft4_inv<<<16384, 256, 0, stream>>>(pre, pim);
    fft_n_inv<<<4096, 256, 0, stream>>>(pre, pim);
}

// Round 2
// 1157.244 us; speedup vs baseline: 1.7181x; 1.7181x over previous
//
#include <hip/hip_runtime.h>
#include <math.h>

#define TWO_PI 6.283185307179586f

typedef __attribute__((ext_vector_type(8))) short bf16x8;
typedef __attribute__((ext_vector_type(4))) float f32x4;

__device__ __forceinline__ short f2bf(float f) {
    unsigned u = __float_as_uint(f);
    unsigned r = (u + 0x7FFFu + ((u >> 16) & 1u)) >> 16;   // RNE
    return (short)r;
}

// ---------------------------------------------------------------------------
// In-LDS 4096-point radix-2 DIT FFT (input already bit-reversed in LDS).
// sgn = -1 forward, +1 inverse. 256 threads, 8 butterflies/thread/stage.
// ---------------------------------------------------------------------------
__device__ __forceinline__ void fft4096(float* lre, float* lim, float sgn) {
    const int tid = threadIdx.x;
    for (int s = 1; s <= 12; ++s) {
        const int half = 1 << (s - 1);
        const float fac = sgn * TWO_PI / (float)(half << 1);
        __syncthreads();
        for (int idx = tid; idx < 2048; idx += 256) {
            const int j    = idx & (half - 1);
            const int base = ((idx >> (s - 1)) << s) + j;
            const int pair = base + half;
            float si, co;
            sincosf((float)j * fac, &si, &co);
            const float ur = lre[base], ui = lim[base];
            const float vr = lre[pair], vi = lim[pair];
            const float tr = vr * co - vi * si;
            const float ti = vr * si + vi * co;
            lre[base] = ur + tr;
            lim[base] = ui + ti;
            lre[pair] = ur - tr;
            lim[pair] = ui - ti;
        }
    }
    __syncthreads();
}

// K1: forward FFT along N for one (batch, channel) column. x real input.
extern "C" __global__ void __launch_bounds__(256)
fft_n_fwd(const float* __restrict__ x, float* __restrict__ pre, float* __restrict__ pim) {
    __shared__ float lre[4096];
    __shared__ float lim[4096];
    const int col = blockIdx.x;                       // b*512 + c
    const size_t base = (size_t)(col >> 9) * (4096ull * 512ull) + (size_t)(col & 511);
    for (int n = threadIdx.x; n < 4096; n += 256) {
        const float v = x[base + (size_t)n * 512];
        const int r = __brev((unsigned)n) >> 20;
        lre[r] = v;
        lim[r] = 0.0f;
    }
    fft4096(lre, lim, -1.0f);
    for (int n = threadIdx.x; n < 4096; n += 256) {
        pre[base + (size_t)n * 512] = lre[n];
        pim[base + (size_t)n * 512] = lim[n];
    }
}

// K6: inverse FFT along N; writes REAL part only (into pre == d_out).
extern "C" __global__ void __launch_bounds__(256)
fft_n_inv(float* __restrict__ pre, const float* __restrict__ pim) {
    __shared__ float lre[4096];
    __shared__ float lim[4096];
    const int col = blockIdx.x;
    const size_t base = (size_t)(col >> 9) * (4096ull * 512ull) + (size_t)(col & 511);
    for (int n = threadIdx.x; n < 4096; n += 256) {
        const int r = __brev((unsigned)n) >> 20;
        lre[r] = pre[base + (size_t)n * 512];
        lim[r] = pim[base + (size_t)n * 512];
    }
    fft4096(lre, lim, +1.0f);
    for (int n = threadIdx.x; n < 4096; n += 256) {
        pre[base + (size_t)n * 512] = lre[n];
    }
}

// K2: forward 4-point DFT across blocks, in place, with ortho scale 1/128.
extern "C" __global__ void __launch_bounds__(256)
fft4_fwd(float* __restrict__ re, float* __restrict__ im) {
    const size_t g = (size_t)blockIdx.x * 256 + threadIdx.x;   // < 8*4096*128
    const size_t d = g & 127;
    const size_t rown = g >> 7;                                 // b*4096 + n
    const size_t a0 = rown * 512 + d;
    const float r0 = re[a0], r1 = re[a0 + 128], r2 = re[a0 + 256], r3 = re[a0 + 384];
    const float m0 = im[a0], m1 = im[a0 + 128], m2 = im[a0 + 256], m3 = im[a0 + 384];
    const float s = 1.0f / 128.0f;
    re[a0]       = (r0 + r1 + r2 + r3) * s;  im[a0]       = (m0 + m1 + m2 + m3) * s;
    re[a0 + 128] = (r0 + m1 - r2 - m3) * s;  im[a0 + 128] = (m0 - r1 - m2 + r3) * s;
    re[a0 + 256] = (r0 - r1 + r2 - r3) * s;  im[a0 + 256] = (m0 - m1 + m2 - m3) * s;
    re[a0 + 384] = (r0 - m1 - r2 + m3) * s;  im[a0 + 384] = (m0 + r1 - m2 - r3) * s;
}

// K5: inverse 4-point DFT across blocks, in place, with ortho scale 1/128.
extern "C" __global__ void __launch_bounds__(256)
fft4_inv(float* __restrict__ re, float* __restrict__ im) {
    const size_t g = (size_t)blockIdx.x * 256 + threadIdx.x;
    const size_t d = g & 127;
    const size_t rown = g >> 7;
    const size_t a0 = rown * 512 + d;
    const float r0 = re[a0], r1 = re[a0 + 128], r2 = re[a0 + 256], r3 = re[a0 + 384];
    const float m0 = im[a0], m1 = im[a0 + 128], m2 = im[a0 + 256], m3 = im[a0 + 384];
    const float s = 1.0f / 128.0f;
    re[a0]       = (r0 + r1 + r2 + r3) * s;  im[a0]       = (m0 + m1 + m2 + m3) * s;
    re[a0 + 128] = (r0 - m1 - r2 + m3) * s;  im[a0 + 128] = (m0 + r1 - m2 - r3) * s;
    re[a0 + 256] = (r0 - r1 + r2 - r3) * s;  im[a0 + 256] = (m0 - m1 + m2 - m3) * s;
    re[a0 + 384] = (r0 + m1 - r2 - m3) * s;  im[a0 + 384] = (m0 - r1 - m2 + r3) * s;
}

// ---------------------------------------------------------------------------
// MFMA block-diagonal complex MLP layer, in place.
// Real GEMM formulation: out[:,0:128]=r_out, out[:,128:256]=i_out,
//   A = [re | im] (K=256), W_big[k][n] per 2x2 complex structure.
// 512 threads = 8 waves; wave w owns cols [32w, 32w+32); wg owns 64-row tiles.
// A tile staged to LDS in bf16 with XOR swizzle (T2); W fragments live in
// registers for the whole kernel (loaded once from fp32 global, L2-hot).
// ---------------------------------------------------------------------------
#define MITER 4

template<int LAYER>
__global__ void __launch_bounds__(512)
mlp_mfma(float* __restrict__ re, float* __restrict__ im,
         const float* __restrict__ w, const float* __restrict__ bias) {
    __shared__ __align__(16) char As[64 * 256 * 2];   // 32 KB bf16, swizzled

    const int blk  = blockIdx.y;
    const int tid  = threadIdx.x;
    const int wave = tid >> 6;
    const int lane = tid & 63;
    const int lrow = lane & 15;   // row (A) / col (B,D) within fragment
    const int lk   = lane >> 4;   // k-chunk 0..3

    // ---- load B fragments once: Bf[nt][ks], lane holds W_big[kbase..+7][n]
    bf16x8 Bf[2][8];
#pragma unroll
    for (int nt = 0; nt < 2; ++nt) {
        const int n = wave * 32 + nt * 16 + lrow;     // 0..255
#pragma unroll
        for (int ks = 0; ks < 8; ++ks) {
            const int kbase = ks * 32 + lk * 8;
            bf16x8 pv;
#pragma unroll
            for (int i = 0; i < 8; ++i) {
                const int k = kbase + i;
                float v;
                if (k < 128) {
                    v = (n < 128) ? w[blk * 16384 + k * 128 + n]
                                  : w[65536 + blk * 16384 + k * 128 + (n - 128)];
                } else {
                    v = (n < 128) ? -w[65536 + blk * 16384 + (k - 128) * 128 + n]
                                  :  w[blk * 16384 + (k - 128) * 128 + (n - 128)];
                }
                pv[i] = f2bf(v);
            }
            Bf[nt][ks] = pv;
        }
    }

    // biases per nt
    float bv[2];
#pragma unroll
    for (int nt = 0; nt < 2; ++nt) {
        const int n = wave * 32 + nt * 16 + lrow;
        bv[nt] = (n < 128) ? bias[blk * 128 + n] : bias[512 + blk * 128 + (n - 128)];
    }

    for (int t = 0; t < MITER; ++t) {
        const int rowbase = (blockIdx.x * MITER + t) * 64;

        // ---- stage A tile: 64 rows x 256 k (re then im), fp32 -> bf16
        for (int idx = tid; idx < 64 * 32; idx += 512) {
            const int row = idx >> 5;
            const int kg  = idx & 31;
            const int k0  = kg * 8;
            const float* src = (k0 < 128) ? re : im;
            const size_t g = (size_t)(rowbase + row) * 512 + blk * 128 + (k0 & 127);
            const float4 v0 = *(const float4*)(src + g);
            const float4 v1 = *(const float4*)(src + g + 4);
            bf16x8 pv;
            pv[0] = f2bf(v0.x); pv[1] = f2bf(v0.y); pv[2] = f2bf(v0.z); pv[3] = f2bf(v0.w);
            pv[4] = f2bf(v1.x); pv[5] = f2bf(v1.y); pv[6] = f2bf(v1.z); pv[7] = f2bf(v1.w);
            const unsigned byteoff = ((unsigned)(row * 512 + k0 * 2)) ^ ((unsigned)((row & 7) << 4));
            *(bf16x8*)(As + byteoff) = pv;
        }
        __syncthreads();

        // ---- MFMA: 4 m-frags x 2 n-frags, K=256 in 8 steps
        f32x4 acc[4][2];
#pragma unroll
        for (int mt = 0; mt < 4; ++mt)
#pragma unroll
            for (int nt = 0; nt < 2; ++nt)
                acc[mt][nt] = (f32x4){0.f, 0.f, 0.f, 0.f};

#pragma unroll
        for (int ks = 0; ks < 8; ++ks) {
            bf16x8 af[4];
#pragma unroll
            for (int mt = 0; mt < 4; ++mt) {
                const int row = mt * 16 + lrow;
                const int k0  = ks * 32 + lk * 8;
                const unsigned byteoff =
                    ((unsigned)(row * 512 + k0 * 2)) ^ ((unsigned)((row & 7) << 4));
                af[mt] = *(const bf16x8*)(As + byteoff);
            }
#pragma unroll
            for (int mt = 0; mt < 4; ++mt)
#pragma unroll
                for (int nt = 0; nt < 2; ++nt)
                    acc[mt][nt] = __builtin_amdgcn_mfma_f32_16x16x32_bf16(
                        af[mt], Bf[nt][ks], acc[mt][nt], 0, 0, 0);
        }
        __syncthreads();   // LDS reads done before next tile's staging

        // ---- epilogue: bias + activation, scatter to re/im planes
#pragma unroll
        for (int nt = 0; nt < 2; ++nt) {
            const int n = wave * 32 + nt * 16 + lrow;
            float* dst = (n < 128) ? re : im;
            const int col = blk * 128 + (n & 127);
#pragma unroll
            for (int mt = 0; mt < 4; ++mt) {
#pragma unroll
                for (int r = 0; r < 4; ++r) {
                    const int row = rowbase + mt * 16 + lk * 4 + r;
                    float v = acc[mt][nt][r] + bv[nt];
                    if (LAYER == 1) {
                        v = fmaxf(v, 0.0f);
                    } else {
                        v = (v > 0.01f) ? v - 0.01f : ((v < -0.01f) ? v + 0.01f : 0.0f);
                    }
                    dst[(size_t)row * 512 + col] = v;
                }
            }
        }
    }
}

extern "C" void kernel_launch(void* const* d_in, const int* in_sizes, int n_in,
                              void* d_out, int out_size, void* d_ws, size_t ws_size,
                              hipStream_t stream) {
    const float* x  = (const float*)d_in[0];
    const float* w1 = (const float*)d_in[1];
    const float* w2 = (const float*)d_in[2];
    const float* b1 = (const float*)d_in[3];
    const float* b2 = (const float*)d_in[4];

    float* pre = (float*)d_out;   // real plane; ends as the final output
    float* pim = (float*)d_ws;    // imag plane (64 MiB of workspace)

    // forward FFT2 (ortho): length-4096 FFT per column, then 4-point across blocks
    fft_n_fwd<<<4096, 256, 0, stream>>>(x, pre, pim);
    fft4_fwd<<<16384, 256, 0, stream>>>(pre, pim);

    // block-diagonal complex MLP via MFMA, in place
    mlp_mfma<1><<<dim3(32768 / (64 * MITER), 4), 512, 0, stream>>>(pre, pim, w1, b1);
    mlp_mfma<2><<<dim3(32768 / (64 * MITER), 4), 512, 0, stream>>>(pre, pim, w2, b2);

    // inverse FFT2 (ortho): 4-point across blocks, then length-4096 per column
    fft4_inv<<<16384, 256, 0, stream>>>(pre, pim);
    fft_n_inv<<<4096, 256, 0, stream>>>(pre, pim);
}

// Round 3
// 451.457 us; speedup vs baseline: 4.4041x; 2.5634x over previous
//
#include <hip/hip_runtime.h>
#include <math.h>

#define TWO_PI 6.283185307179586f

typedef __attribute__((ext_vector_type(8))) short bf16x8;
typedef __attribute__((ext_vector_type(4))) float f32x4;

__device__ __forceinline__ short f2bf(float f) {
    unsigned u = __float_as_uint(f);
    unsigned r = (u + 0x7FFFu + ((u >> 16) & 1u)) >> 16;   // RNE
    return (short)r;
}

__device__ __forceinline__ int bitrev6(int s) { return (int)(__brev((unsigned)s) >> 26); }

// ---------------------------------------------------------------------------
// 64-point FFTs across 128 channels in LDS tile [64][128].
// Table: wre[m]=cos(2pi m/64), wim[m]=-sin(2pi m/64)  (forward twiddle W64^m).
// DIF: natural in -> bit-reversed out (forward sign).
// DIT: bit-reversed in -> natural out (inverse sign, conj twiddle).
// Thread split: c = tid&127 (channel), h = tid>>7 picks 16 of 32 butterflies.
// ---------------------------------------------------------------------------
__device__ __forceinline__ void fft64_dif(float (*Lre)[128], float (*Lim)[128],
                                          const float* wre, const float* wim,
                                          int c, int h) {
#pragma unroll
    for (int t = 0; t < 6; ++t) {
        const int span = 32 >> t;
        __syncthreads();
#pragma unroll
        for (int jj = 0; jj < 16; ++jj) {
            const int jl = h * 16 + jj;
            const int g  = jl >> (5 - t);
            const int j  = jl & (span - 1);
            const int a  = (g << (6 - t)) + j;
            const int bb = a + span;
            const int m  = j << t;
            const float w_r = wre[m], w_i = wim[m];
            const float ar = Lre[a][c],  ai = Lim[a][c];
            const float br = Lre[bb][c], bi = Lim[bb][c];
            Lre[a][c] = ar + br;
            Lim[a][c] = ai + bi;
            const float dr = ar - br, di = ai - bi;
            Lre[bb][c] = dr * w_r - di * w_i;
            Lim[bb][c] = dr * w_i + di * w_r;
        }
    }
    __syncthreads();
}

__device__ __forceinline__ void fft64_dit_inv(float (*Lre)[128], float (*Lim)[128],
                                              const float* wre, const float* wim,
                                              int c, int h) {
#pragma unroll
    for (int t = 0; t < 6; ++t) {
        const int span = 1 << t;
        __syncthreads();
#pragma unroll
        for (int jj = 0; jj < 16; ++jj) {
            const int jl = h * 16 + jj;
            const int g  = jl >> t;
            const int j  = jl & (span - 1);
            const int a  = (g << (t + 1)) + j;
            const int bb = a + span;
            const int m  = j << (5 - t);
            const float w_r = wre[m], w_i = -wim[m];     // conj -> inverse sign
            const float br = Lre[bb][c], bi = Lim[bb][c];
            const float tr = br * w_r - bi * w_i;
            const float ti = br * w_i + bi * w_r;
            const float ar = Lre[a][c], ai = Lim[a][c];
            Lre[a][c]  = ar + tr;
            Lim[a][c]  = ai + ti;
            Lre[bb][c] = ar - tr;
            Lim[bb][c] = ai - ti;
        }
    }
    __syncthreads();
}

// Channel tiling: workgroup covers channels {blk*128 + ct*32 + d : blk<4, d<32}
// (local col = blk*32 + d), so all 4 fft4-blocks are present per d.
// idx in [0,2048): slot = idx>>5, q = idx&31, blk = q>>3, f4 = q&7.
#define DECODE_BCT() \
    const int b  = blockIdx.x >> 8; \
    const int dg = (blockIdx.x >> 2) & 63; \
    const int ct = blockIdx.x & 3;

#define GADDR(slot, blk, f4) \
    (((size_t)(b * 4096 + (slot)) * 512) + (size_t)((blk) * 128 + ct * 32 + (f4) * 4))

// ---- forward pass A: FFT over n1 (slots 64*n1+dg), twiddle, in x -> out pre/pim
extern "C" __global__ void __launch_bounds__(256)
fft_fwd_a(const float* __restrict__ x, float* __restrict__ pre, float* __restrict__ pim) {
    __shared__ __align__(16) float Lre[64][128];
    __shared__ __align__(16) float Lim[64][128];
    __shared__ float wre[32], wim[32];
    const int tid = threadIdx.x;
    if (tid < 32) {
        float s, c;
        sincosf(TWO_PI * (float)tid / 64.0f, &s, &c);
        wre[tid] = c; wim[tid] = -s;
    }
    DECODE_BCT();   // dg = n2
    for (int idx = tid; idx < 2048; idx += 256) {
        const int n1 = idx >> 5, q = idx & 31, blk = q >> 3, f4 = q & 7;
        const int cl = blk * 32 + f4 * 4;
        const float4 v = *(const float4*)(x + GADDR(n1 * 64 + dg, blk, f4));
        *(float4*)&Lre[n1][cl] = v;
        float4 z; z.x = 0.f; z.y = 0.f; z.z = 0.f; z.w = 0.f;
        *(float4*)&Lim[n1][cl] = z;
    }
    fft64_dif(Lre, Lim, wre, wim, tid & 127, tid >> 7);
    for (int idx = tid; idx < 2048; idx += 256) {
        const int s1 = idx >> 5, q = idx & 31, blk = q >> 3, f4 = q & 7;
        const int cl = blk * 32 + f4 * 4;
        const int k1 = bitrev6(s1);
        float sn, cs;
        sincosf(-(TWO_PI / 4096.0f) * (float)(dg * k1), &sn, &cs);
        const float4 vr = *(const float4*)&Lre[s1][cl];
        const float4 vi = *(const float4*)&Lim[s1][cl];
        float4 orr, oii;
        orr.x = vr.x * cs - vi.x * sn;  oii.x = vr.x * sn + vi.x * cs;
        orr.y = vr.y * cs - vi.y * sn;  oii.y = vr.y * sn + vi.y * cs;
        orr.z = vr.z * cs - vi.z * sn;  oii.z = vr.z * sn + vi.z * cs;
        orr.w = vr.w * cs - vi.w * sn;  oii.w = vr.w * sn + vi.w * cs;
        const size_t g = GADDR(s1 * 64 + dg, blk, f4);
        *(float4*)(pre + g) = orr;
        *(float4*)(pim + g) = oii;
    }
}

// ---- forward pass B: FFT over n2 (slots 64*dg+n2 contiguous) + fused fft4_fwd (x1/128)
extern "C" __global__ void __launch_bounds__(256)
fft_fwd_b(float* __restrict__ pre, float* __restrict__ pim) {
    __shared__ __align__(16) float Lre[64][128];
    __shared__ __align__(16) float Lim[64][128];
    __shared__ float wre[32], wim[32];
    const int tid = threadIdx.x;
    if (tid < 32) {
        float s, c;
        sincosf(TWO_PI * (float)tid / 64.0f, &s, &c);
        wre[tid] = c; wim[tid] = -s;
    }
    DECODE_BCT();   // dg = s1
    for (int idx = tid; idx < 2048; idx += 256) {
        const int n2 = idx >> 5, q = idx & 31, blk = q >> 3, f4 = q & 7;
        const int cl = blk * 32 + f4 * 4;
        const size_t g = GADDR(dg * 64 + n2, blk, f4);
        *(float4*)&Lre[n2][cl] = *(const float4*)(pre + g);
        *(float4*)&Lim[n2][cl] = *(const float4*)(pim + g);
    }
    fft64_dif(Lre, Lim, wre, wim, tid & 127, tid >> 7);
    // fused fft4 across blocks + ortho scale
    for (int idx = tid; idx < 2048; idx += 256) {
        const int s = idx >> 5, dl = idx & 31;
        const float r0 = Lre[s][dl], r1 = Lre[s][dl + 32], r2 = Lre[s][dl + 64], r3 = Lre[s][dl + 96];
        const float m0 = Lim[s][dl], m1 = Lim[s][dl + 32], m2 = Lim[s][dl + 64], m3 = Lim[s][dl + 96];
        const float sc = 1.0f / 128.0f;
        Lre[s][dl]      = (r0 + r1 + r2 + r3) * sc;  Lim[s][dl]      = (m0 + m1 + m2 + m3) * sc;
        Lre[s][dl + 32] = (r0 + m1 - r2 - m3) * sc;  Lim[s][dl + 32] = (m0 - r1 - m2 + r3) * sc;
        Lre[s][dl + 64] = (r0 - r1 + r2 - r3) * sc;  Lim[s][dl + 64] = (m0 - m1 + m2 - m3) * sc;
        Lre[s][dl + 96] = (r0 - m1 - r2 + m3) * sc;  Lim[s][dl + 96] = (m0 + r1 - m2 - r3) * sc;
    }
    __syncthreads();
    for (int idx = tid; idx < 2048; idx += 256) {
        const int s2 = idx >> 5, q = idx & 31, blk = q >> 3, f4 = q & 7;
        const int cl = blk * 32 + f4 * 4;
        const size_t g = GADDR(dg * 64 + s2, blk, f4);
        *(float4*)(pre + g) = *(const float4*)&Lre[s2][cl];
        *(float4*)(pim + g) = *(const float4*)&Lim[s2][cl];
    }
}

// ---- inverse pass A: fused fft4_inv (x1/128), then inverse FFT over k2, twiddle
extern "C" __global__ void __launch_bounds__(256)
fft_inv_a(float* __restrict__ pre, float* __restrict__ pim) {
    __shared__ __align__(16) float Lre[64][128];
    __shared__ __align__(16) float Lim[64][128];
    __shared__ float wre[32], wim[32];
    const int tid = threadIdx.x;
    if (tid < 32) {
        float s, c;
        sincosf(TWO_PI * (float)tid / 64.0f, &s, &c);
        wre[tid] = c; wim[tid] = -s;
    }
    DECODE_BCT();   // dg = s1
    for (int idx = tid; idx < 2048; idx += 256) {
        const int s2 = idx >> 5, q = idx & 31, blk = q >> 3, f4 = q & 7;
        const int cl = blk * 32 + f4 * 4;
        const size_t g = GADDR(dg * 64 + s2, blk, f4);
        *(float4*)&Lre[s2][cl] = *(const float4*)(pre + g);
        *(float4*)&Lim[s2][cl] = *(const float4*)(pim + g);
    }
    __syncthreads();
    // fused inverse fft4 across blocks + ortho scale
    for (int idx = tid; idx < 2048; idx += 256) {
        const int s = idx >> 5, dl = idx & 31;
        const float r0 = Lre[s][dl], r1 = Lre[s][dl + 32], r2 = Lre[s][dl + 64], r3 = Lre[s][dl + 96];
        const float m0 = Lim[s][dl], m1 = Lim[s][dl + 32], m2 = Lim[s][dl + 64], m3 = Lim[s][dl + 96];
        const float sc = 1.0f / 128.0f;
        Lre[s][dl]      = (r0 + r1 + r2 + r3) * sc;  Lim[s][dl]      = (m0 + m1 + m2 + m3) * sc;
        Lre[s][dl + 32] = (r0 - m1 - r2 + m3) * sc;  Lim[s][dl + 32] = (m0 + r1 - m2 - r3) * sc;
        Lre[s][dl + 64] = (r0 - r1 + r2 - r3) * sc;  Lim[s][dl + 64] = (m0 - m1 + m2 - m3) * sc;
        Lre[s][dl + 96] = (r0 + m1 - r2 - m3) * sc;  Lim[s][dl + 96] = (m0 - r1 - m2 + r3) * sc;
    }
    fft64_dit_inv(Lre, Lim, wre, wim, tid & 127, tid >> 7);
    for (int idx = tid; idx < 2048; idx += 256) {
        const int n2 = idx >> 5, q = idx & 31, blk = q >> 3, f4 = q & 7;
        const int cl = blk * 32 + f4 * 4;
        const int k1 = bitrev6(dg);
        float sn, cs;
        sincosf((TWO_PI / 4096.0f) * (float)(n2 * k1), &sn, &cs);
        const float4 vr = *(const float4*)&Lre[n2][cl];
        const float4 vi = *(const float4*)&Lim[n2][cl];
        float4 orr, oii;
        orr.x = vr.x * cs - vi.x * sn;  oii.x = vr.x * sn + vi.x * cs;
        orr.y = vr.y * cs - vi.y * sn;  oii.y = vr.y * sn + vi.y * cs;
        orr.z = vr.z * cs - vi.z * sn;  oii.z = vr.z * sn + vi.z * cs;
        orr.w = vr.w * cs - vi.w * sn;  oii.w = vr.w * sn + vi.w * cs;
        const size_t g = GADDR(dg * 64 + n2, blk, f4);
        *(float4*)(pre + g) = orr;
        *(float4*)(pim + g) = oii;
    }
}

// ---- inverse pass B: inverse FFT over k1 (slots 64*s1+dg), write REAL only
extern "C" __global__ void __launch_bounds__(256)
fft_inv_b(float* __restrict__ pre, const float* __restrict__ pim) {
    __shared__ __align__(16) float Lre[64][128];
    __shared__ __align__(16) float Lim[64][128];
    __shared__ float wre[32], wim[32];
    const int tid = threadIdx.x;
    if (tid < 32) {
        float s, c;
        sincosf(TWO_PI * (float)tid / 64.0f, &s, &c);
        wre[tid] = c; wim[tid] = -s;
    }
    DECODE_BCT();   // dg = n2
    for (int idx = tid; idx < 2048; idx += 256) {
        const int s1 = idx >> 5, q = idx & 31, blk = q >> 3, f4 = q & 7;
        const int cl = blk * 32 + f4 * 4;
        const size_t g = GADDR(s1 * 64 + dg, blk, f4);
        *(float4*)&Lre[s1][cl] = *(const float4*)(pre + g);
        *(float4*)&Lim[s1][cl] = *(const float4*)(pim + g);
    }
    fft64_dit_inv(Lre, Lim, wre, wim, tid & 127, tid >> 7);
    for (int idx = tid; idx < 2048; idx += 256) {
        const int n1 = idx >> 5, q = idx & 31, blk = q >> 3, f4 = q & 7;
        const int cl = blk * 32 + f4 * 4;
        *(float4*)(pre + GADDR(n1 * 64 + dg, blk, f4)) = *(const float4*)&Lre[n1][cl];
    }
}

// ---------------------------------------------------------------------------
// MFMA block-diagonal complex MLP layer, in place (unchanged from round 1).
// ---------------------------------------------------------------------------
#define MITER 4

template<int LAYER>
__global__ void __launch_bounds__(512)
mlp_mfma(float* __restrict__ re, float* __restrict__ im,
         const float* __restrict__ w, const float* __restrict__ bias) {
    __shared__ __align__(16) char As[64 * 256 * 2];   // 32 KB bf16, swizzled

    const int blk  = blockIdx.y;
    const int tid  = threadIdx.x;
    const int wave = tid >> 6;
    const int lane = tid & 63;
    const int lrow = lane & 15;
    const int lk   = lane >> 4;

    bf16x8 Bf[2][8];
#pragma unroll
    for (int nt = 0; nt < 2; ++nt) {
        const int n = wave * 32 + nt * 16 + lrow;
#pragma unroll
        for (int ks = 0; ks < 8; ++ks) {
            const int kbase = ks * 32 + lk * 8;
            bf16x8 pv;
#pragma unroll
            for (int i = 0; i < 8; ++i) {
                const int k = kbase + i;
                float v;
                if (k < 128) {
                    v = (n < 128) ? w[blk * 16384 + k * 128 + n]
                                  : w[65536 + blk * 16384 + k * 128 + (n - 128)];
                } else {
                    v = (n < 128) ? -w[65536 + blk * 16384 + (k - 128) * 128 + n]
                                  :  w[blk * 16384 + (k - 128) * 128 + (n - 128)];
                }
                pv[i] = f2bf(v);
            }
            Bf[nt][ks] = pv;
        }
    }

    float bv[2];
#pragma unroll
    for (int nt = 0; nt < 2; ++nt) {
        const int n = wave * 32 + nt * 16 + lrow;
        bv[nt] = (n < 128) ? bias[blk * 128 + n] : bias[512 + blk * 128 + (n - 128)];
    }

    for (int t = 0; t < MITER; ++t) {
        const int rowbase = (blockIdx.x * MITER + t) * 64;

        for (int idx = tid; idx < 64 * 32; idx += 512) {
            const int row = idx >> 5;
            const int kg  = idx & 31;
            const int k0  = kg * 8;
            const float* src = (k0 < 128) ? re : im;
            const size_t g = (size_t)(rowbase + row) * 512 + blk * 128 + (k0 & 127);
            const float4 v0 = *(const float4*)(src + g);
            const float4 v1 = *(const float4*)(src + g + 4);
            bf16x8 pv;
            pv[0] = f2bf(v0.x); pv[1] = f2bf(v0.y); pv[2] = f2bf(v0.z); pv[3] = f2bf(v0.w);
            pv[4] = f2bf(v1.x); pv[5] = f2bf(v1.y); pv[6] = f2bf(v1.z); pv[7] = f2bf(v1.w);
            const unsigned byteoff = ((unsigned)(row * 512 + k0 * 2)) ^ ((unsigned)((row & 7) << 4));
            *(bf16x8*)(As + byteoff) = pv;
        }
        __syncthreads();

        f32x4 acc[4][2];
#pragma unroll
        for (int mt = 0; mt < 4; ++mt)
#pragma unroll
            for (int nt = 0; nt < 2; ++nt)
                acc[mt][nt] = (f32x4){0.f, 0.f, 0.f, 0.f};

#pragma unroll
        for (int ks = 0; ks < 8; ++ks) {
            bf16x8 af[4];
#pragma unroll
            for (int mt = 0; mt < 4; ++mt) {
                const int row = mt * 16 + lrow;
                const int k0  = ks * 32 + lk * 8;
                const unsigned byteoff =
                    ((unsigned)(row * 512 + k0 * 2)) ^ ((unsigned)((row & 7) << 4));
                af[mt] = *(const bf16x8*)(As + byteoff);
            }
#pragma unroll
            for (int mt = 0; mt < 4; ++mt)
#pragma unroll
                for (int nt = 0; nt < 2; ++nt)
                    acc[mt][nt] = __builtin_amdgcn_mfma_f32_16x16x32_bf16(
                        af[mt], Bf[nt][ks], acc[mt][nt], 0, 0, 0);
        }
        __syncthreads();

#pragma unroll
        for (int nt = 0; nt < 2; ++nt) {
            const int n = wave * 32 + nt * 16 + lrow;
            float* dst = (n < 128) ? re : im;
            const int col = blk * 128 + (n & 127);
#pragma unroll
            for (int mt = 0; mt < 4; ++mt) {
#pragma unroll
                for (int r = 0; r < 4; ++r) {
                    const int row = rowbase + mt * 16 + lk * 4 + r;
                    float v = acc[mt][nt][r] + bv[nt];
                    if (LAYER == 1) {
                        v = fmaxf(v, 0.0f);
                    } else {
                        v = (v > 0.01f) ? v - 0.01f : ((v < -0.01f) ? v + 0.01f : 0.0f);
                    }
                    dst[(size_t)row * 512 + col] = v;
                }
            }
        }
    }
}

extern "C" void kernel_launch(void* const* d_in, const int* in_sizes, int n_in,
                              void* d_out, int out_size, void* d_ws, size_t ws_size,
                              hipStream_t stream) {
    const float* x  = (const float*)d_in[0];
    const float* w1 = (const float*)d_in[1];
    const float* w2 = (const float*)d_in[2];
    const float* b1 = (const float*)d_in[3];
    const float* b2 = (const float*)d_in[4];

    float* pre = (float*)d_out;   // real plane; ends as the final output
    float* pim = (float*)d_ws;    // imag plane (64 MiB of workspace)

    // forward FFT2 (ortho): 4096 = 64x64 four-step; fft4+scale fused into pass B
    fft_fwd_a<<<2048, 256, 0, stream>>>(x, pre, pim);
    fft_fwd_b<<<2048, 256, 0, stream>>>(pre, pim);

    // block-diagonal complex MLP via MFMA, in place (frequency order-agnostic)
    mlp_mfma<1><<<dim3(32768 / (64 * MITER), 4), 512, 0, stream>>>(pre, pim, w1, b1);
    mlp_mfma<2><<<dim3(32768 / (64 * MITER), 4), 512, 0, stream>>>(pre, pim, w2, b2);

    // inverse FFT2 (ortho): fft4_inv+scale fused into pass A, then finish over n
    fft_inv_a<<<2048, 256, 0, stream>>>(pre, pim);
    fft_inv_b<<<2048, 256, 0, stream>>>(pre, pim);
}

// Round 4
// 365.531 us; speedup vs baseline: 5.4394x; 1.2351x over previous
//
#include <hip/hip_runtime.h>
#include <math.h>

#define TWO_PI 6.283185307179586f

typedef __attribute__((ext_vector_type(8))) short bf16x8;
typedef __attribute__((ext_vector_type(4))) float f32x4;

__device__ __forceinline__ short f2bf(float f) {
    unsigned u = __float_as_uint(f);
    unsigned r = (u + 0x7FFFu + ((u >> 16) & 1u)) >> 16;   // RNE
    return (short)r;
}

__device__ __forceinline__ int bitrev6(int s) { return (int)(__brev((unsigned)s) >> 26); }

// ---------------------------------------------------------------------------
// 64-point FFTs across 128 channels in LDS tile [64][128]. 512 threads:
// c = tid&127 (channel), h = tid>>7 (0..3) picks 8 of 32 butterflies/stage.
// ---------------------------------------------------------------------------
__device__ __forceinline__ void fft64_dif(float (*Lre)[128], float (*Lim)[128],
                                          const float* wre, const float* wim,
                                          int c, int h) {
#pragma unroll
    for (int t = 0; t < 6; ++t) {
        const int span = 32 >> t;
        __syncthreads();
#pragma unroll
        for (int jj = 0; jj < 8; ++jj) {
            const int jl = h * 8 + jj;
            const int g  = jl >> (5 - t);
            const int j  = jl & (span - 1);
            const int a  = (g << (6 - t)) + j;
            const int bb = a + span;
            const int m  = j << t;
            const float w_r = wre[m], w_i = wim[m];
            const float ar = Lre[a][c],  ai = Lim[a][c];
            const float br = Lre[bb][c], bi = Lim[bb][c];
            Lre[a][c] = ar + br;
            Lim[a][c] = ai + bi;
            const float dr = ar - br, di = ai - bi;
            Lre[bb][c] = dr * w_r - di * w_i;
            Lim[bb][c] = dr * w_i + di * w_r;
        }
    }
    __syncthreads();
}

__device__ __forceinline__ void fft64_dit_inv(float (*Lre)[128], float (*Lim)[128],
                                              const float* wre, const float* wim,
                                              int c, int h) {
#pragma unroll
    for (int t = 0; t < 6; ++t) {
        const int span = 1 << t;
        __syncthreads();
#pragma unroll
        for (int jj = 0; jj < 8; ++jj) {
            const int jl = h * 8 + jj;
            const int g  = jl >> t;
            const int j  = jl & (span - 1);
            const int a  = (g << (t + 1)) + j;
            const int bb = a + span;
            const int m  = j << (5 - t);
            const float w_r = wre[m], w_i = -wim[m];     // conj -> inverse sign
            const float br = Lre[bb][c], bi = Lim[bb][c];
            const float tr = br * w_r - bi * w_i;
            const float ti = br * w_i + bi * w_r;
            const float ar = Lre[a][c], ai = Lim[a][c];
            Lre[a][c]  = ar + tr;
            Lim[a][c]  = ai + ti;
            Lre[bb][c] = ar - tr;
            Lim[bb][c] = ai - ti;
        }
    }
    __syncthreads();
}

#define DECODE_BCT() \
    const int b  = blockIdx.x >> 8; \
    const int dg = (blockIdx.x >> 2) & 63; \
    const int ct = blockIdx.x & 3;

#define GADDR(slot, blk, f4) \
    (((size_t)(b * 4096 + (slot)) * 512) + (size_t)((blk) * 128 + ct * 32 + (f4) * 4))

#define SETUP_TABLE() \
    if (tid < 32) { \
        float s_, c_; \
        sincosf(TWO_PI * (float)tid / 64.0f, &s_, &c_); \
        wre[tid] = c_; wim[tid] = -s_; \
    }

// ---- forward pass A: FFT over n1 (slots 64*n1+dg), twiddle, x -> pre/pim
extern "C" __global__ void __launch_bounds__(512)
fft_fwd_a(const float* __restrict__ x, float* __restrict__ pre, float* __restrict__ pim) {
    __shared__ __align__(16) float Lre[64][128];
    __shared__ __align__(16) float Lim[64][128];
    __shared__ float wre[32], wim[32];
    const int tid = threadIdx.x;
    SETUP_TABLE();
    DECODE_BCT();   // dg = n2
    for (int idx = tid; idx < 2048; idx += 512) {
        const int n1 = idx >> 5, q = idx & 31, blk = q >> 3, f4 = q & 7;
        const int cl = blk * 32 + f4 * 4;
        const float4 v = *(const float4*)(x + GADDR(n1 * 64 + dg, blk, f4));
        *(float4*)&Lre[n1][cl] = v;
        float4 z; z.x = 0.f; z.y = 0.f; z.z = 0.f; z.w = 0.f;
        *(float4*)&Lim[n1][cl] = z;
    }
    fft64_dif(Lre, Lim, wre, wim, tid & 127, tid >> 7);
    for (int idx = tid; idx < 2048; idx += 512) {
        const int s1 = idx >> 5, q = idx & 31, blk = q >> 3, f4 = q & 7;
        const int cl = blk * 32 + f4 * 4;
        const int k1 = bitrev6(s1);
        float sn, cs;
        sincosf(-(TWO_PI / 4096.0f) * (float)(dg * k1), &sn, &cs);
        const float4 vr = *(const float4*)&Lre[s1][cl];
        const float4 vi = *(const float4*)&Lim[s1][cl];
        float4 orr, oii;
        orr.x = vr.x * cs - vi.x * sn;  oii.x = vr.x * sn + vi.x * cs;
        orr.y = vr.y * cs - vi.y * sn;  oii.y = vr.y * sn + vi.y * cs;
        orr.z = vr.z * cs - vi.z * sn;  oii.z = vr.z * sn + vi.z * cs;
        orr.w = vr.w * cs - vi.w * sn;  oii.w = vr.w * sn + vi.w * cs;
        const size_t g = GADDR(s1 * 64 + dg, blk, f4);
        *(float4*)(pre + g) = orr;
        *(float4*)(pim + g) = oii;
    }
}

// ---- forward pass B: FFT over n2 (contiguous slots) + fused fft4_fwd (x1/128)
extern "C" __global__ void __launch_bounds__(512)
fft_fwd_b(float* __restrict__ pre, float* __restrict__ pim) {
    __shared__ __align__(16) float Lre[64][128];
    __shared__ __align__(16) float Lim[64][128];
    __shared__ float wre[32], wim[32];
    const int tid = threadIdx.x;
    SETUP_TABLE();
    DECODE_BCT();   // dg = s1
    for (int idx = tid; idx < 2048; idx += 512) {
        const int n2 = idx >> 5, q = idx & 31, blk = q >> 3, f4 = q & 7;
        const int cl = blk * 32 + f4 * 4;
        const size_t g = GADDR(dg * 64 + n2, blk, f4);
        *(float4*)&Lre[n2][cl] = *(const float4*)(pre + g);
        *(float4*)&Lim[n2][cl] = *(const float4*)(pim + g);
    }
    fft64_dif(Lre, Lim, wre, wim, tid & 127, tid >> 7);
    for (int idx = tid; idx < 2048; idx += 512) {
        const int s = idx >> 5, dl = idx & 31;
        const float r0 = Lre[s][dl], r1 = Lre[s][dl + 32], r2 = Lre[s][dl + 64], r3 = Lre[s][dl + 96];
        const float m0 = Lim[s][dl], m1 = Lim[s][dl + 32], m2 = Lim[s][dl + 64], m3 = Lim[s][dl + 96];
        const float sc = 1.0f / 128.0f;
        Lre[s][dl]      = (r0 + r1 + r2 + r3) * sc;  Lim[s][dl]      = (m0 + m1 + m2 + m3) * sc;
        Lre[s][dl + 32] = (r0 + m1 - r2 - m3) * sc;  Lim[s][dl + 32] = (m0 - r1 - m2 + r3) * sc;
        Lre[s][dl + 64] = (r0 - r1 + r2 - r3) * sc;  Lim[s][dl + 64] = (m0 - m1 + m2 - m3) * sc;
        Lre[s][dl + 96] = (r0 - m1 - r2 + m3) * sc;  Lim[s][dl + 96] = (m0 + r1 - m2 - r3) * sc;
    }
    __syncthreads();
    for (int idx = tid; idx < 2048; idx += 512) {
        const int s2 = idx >> 5, q = idx & 31, blk = q >> 3, f4 = q & 7;
        const int cl = blk * 32 + f4 * 4;
        const size_t g = GADDR(dg * 64 + s2, blk, f4);
        *(float4*)(pre + g) = *(const float4*)&Lre[s2][cl];
        *(float4*)(pim + g) = *(const float4*)&Lim[s2][cl];
    }
}

// ---- inverse pass A: fused fft4_inv (x1/128), inverse FFT over k2, twiddle
extern "C" __global__ void __launch_bounds__(512)
fft_inv_a(float* __restrict__ pre, float* __restrict__ pim) {
    __shared__ __align__(16) float Lre[64][128];
    __shared__ __align__(16) float Lim[64][128];
    __shared__ float wre[32], wim[32];
    const int tid = threadIdx.x;
    SETUP_TABLE();
    DECODE_BCT();   // dg = s1
    for (int idx = tid; idx < 2048; idx += 512) {
        const int s2 = idx >> 5, q = idx & 31, blk = q >> 3, f4 = q & 7;
        const int cl = blk * 32 + f4 * 4;
        const size_t g = GADDR(dg * 64 + s2, blk, f4);
        *(float4*)&Lre[s2][cl] = *(const float4*)(pre + g);
        *(float4*)&Lim[s2][cl] = *(const float4*)(pim + g);
    }
    __syncthreads();
    for (int idx = tid; idx < 2048; idx += 512) {
        const int s = idx >> 5, dl = idx & 31;
        const float r0 = Lre[s][dl], r1 = Lre[s][dl + 32], r2 = Lre[s][dl + 64], r3 = Lre[s][dl + 96];
        const float m0 = Lim[s][dl], m1 = Lim[s][dl + 32], m2 = Lim[s][dl + 64], m3 = Lim[s][dl + 96];
        const float sc = 1.0f / 128.0f;
        Lre[s][dl]      = (r0 + r1 + r2 + r3) * sc;  Lim[s][dl]      = (m0 + m1 + m2 + m3) * sc;
        Lre[s][dl + 32] = (r0 - m1 - r2 + m3) * sc;  Lim[s][dl + 32] = (m0 + r1 - m2 - r3) * sc;
        Lre[s][dl + 64] = (r0 - r1 + r2 - r3) * sc;  Lim[s][dl + 64] = (m0 - m1 + m2 - m3) * sc;
        Lre[s][dl + 96] = (r0 + m1 - r2 - m3) * sc;  Lim[s][dl + 96] = (m0 - r1 - m2 + r3) * sc;
    }
    fft64_dit_inv(Lre, Lim, wre, wim, tid & 127, tid >> 7);
    for (int idx = tid; idx < 2048; idx += 512) {
        const int n2 = idx >> 5, q = idx & 31, blk = q >> 3, f4 = q & 7;
        const int cl = blk * 32 + f4 * 4;
        const int k1 = bitrev6(dg);
        float sn, cs;
        sincosf((TWO_PI / 4096.0f) * (float)(n2 * k1), &sn, &cs);
        const float4 vr = *(const float4*)&Lre[n2][cl];
        const float4 vi = *(const float4*)&Lim[n2][cl];
        float4 orr, oii;
        orr.x = vr.x * cs - vi.x * sn;  oii.x = vr.x * sn + vi.x * cs;
        orr.y = vr.y * cs - vi.y * sn;  oii.y = vr.y * sn + vi.y * cs;
        orr.z = vr.z * cs - vi.z * sn;  oii.z = vr.z * sn + vi.z * cs;
        orr.w = vr.w * cs - vi.w * sn;  oii.w = vr.w * sn + vi.w * cs;
        const size_t g = GADDR(dg * 64 + n2, blk, f4);
        *(float4*)(pre + g) = orr;
        *(float4*)(pim + g) = oii;
    }
}

// ---- inverse pass B: inverse FFT over k1, write REAL only
extern "C" __global__ void __launch_bounds__(512)
fft_inv_b(float* __restrict__ pre, const float* __restrict__ pim) {
    __shared__ __align__(16) float Lre[64][128];
    __shared__ __align__(16) float Lim[64][128];
    __shared__ float wre[32], wim[32];
    const int tid = threadIdx.x;
    SETUP_TABLE();
    DECODE_BCT();   // dg = n2
    for (int idx = tid; idx < 2048; idx += 512) {
        const int s1 = idx >> 5, q = idx & 31, blk = q >> 3, f4 = q & 7;
        const int cl = blk * 32 + f4 * 4;
        const size_t g = GADDR(s1 * 64 + dg, blk, f4);
        *(float4*)&Lre[s1][cl] = *(const float4*)(pre + g);
        *(float4*)&Lim[s1][cl] = *(const float4*)(pim + g);
    }
    fft64_dit_inv(Lre, Lim, wre, wim, tid & 127, tid >> 7);
    for (int idx = tid; idx < 2048; idx += 512) {
        const int n1 = idx >> 5, q = idx & 31, blk = q >> 3, f4 = q & 7;
        const int cl = blk * 32 + f4 * 4;
        *(float4*)(pre + GADDR(n1 * 64 + dg, blk, f4)) = *(const float4*)&Lre[n1][cl];
    }
}

// ---------------------------------------------------------------------------
// Fused MFMA MLP: layer1 (relu) -> LDS bf16 -> layer2 (softshrink), in place.
// A/Bs layout [64 rows][256 k] bf16 with XOR swizzle ((row&7)<<4 on bytes).
// 512 threads = 8 waves; wave owns output cols [32w,32w+32).
// ---------------------------------------------------------------------------
#define MITER 4

__global__ void __launch_bounds__(512)
mlp_fused(float* __restrict__ re, float* __restrict__ im,
          const float* __restrict__ w1g, const float* __restrict__ w2g,
          const float* __restrict__ b1g, const float* __restrict__ b2g) {
    __shared__ __align__(16) char As[64 * 256 * 2];   // layer-1 input, 32 KB
    __shared__ __align__(16) char Bs[64 * 256 * 2];   // layer-1 output, 32 KB

    const int blk  = blockIdx.y;
    const int tid  = threadIdx.x;
    const int wave = tid >> 6;
    const int lane = tid & 63;
    const int lrow = lane & 15;
    const int lk   = lane >> 4;

    // ---- load B fragments for both layers (W L2-hot, 512 KB total)
    bf16x8 Bf1[2][8], Bf2[2][8];
#pragma unroll
    for (int nt = 0; nt < 2; ++nt) {
        const int n = wave * 32 + nt * 16 + lrow;     // 0..255
#pragma unroll
        for (int ks = 0; ks < 8; ++ks) {
            const int kbase = ks * 32 + lk * 8;
            bf16x8 p1, p2;
#pragma unroll
            for (int i = 0; i < 8; ++i) {
                const int k = kbase + i;
                float v1, v2;
                if (k < 128) {
                    if (n < 128) {
                        v1 = w1g[blk * 16384 + k * 128 + n];
                        v2 = w2g[blk * 16384 + k * 128 + n];
                    } else {
                        v1 = w1g[65536 + blk * 16384 + k * 128 + (n - 128)];
                        v2 = w2g[65536 + blk * 16384 + k * 128 + (n - 128)];
                    }
                } else {
                    if (n < 128) {
                        v1 = -w1g[65536 + blk * 16384 + (k - 128) * 128 + n];
                        v2 = -w2g[65536 + blk * 16384 + (k - 128) * 128 + n];
                    } else {
                        v1 = w1g[blk * 16384 + (k - 128) * 128 + (n - 128)];
                        v2 = w2g[blk * 16384 + (k - 128) * 128 + (n - 128)];
                    }
                }
                p1[i] = f2bf(v1);
                p2[i] = f2bf(v2);
            }
            Bf1[nt][ks] = p1;
            Bf2[nt][ks] = p2;
        }
    }

    float bv1[2], bv2[2];
#pragma unroll
    for (int nt = 0; nt < 2; ++nt) {
        const int n = wave * 32 + nt * 16 + lrow;
        bv1[nt] = (n < 128) ? b1g[blk * 128 + n] : b1g[512 + blk * 128 + (n - 128)];
        bv2[nt] = (n < 128) ? b2g[blk * 128 + n] : b2g[512 + blk * 128 + (n - 128)];
    }

    for (int t = 0; t < MITER; ++t) {
        const int rowbase = (blockIdx.x * MITER + t) * 64;

        // ---- stage layer-1 input: 64 rows x 256 k (re|im), fp32 -> bf16
        for (int idx = tid; idx < 64 * 32; idx += 512) {
            const int row = idx >> 5;
            const int kg  = idx & 31;
            const int k0  = kg * 8;
            const float* src = (k0 < 128) ? re : im;
            const size_t g = (size_t)(rowbase + row) * 512 + blk * 128 + (k0 & 127);
            const float4 v0 = *(const float4*)(src + g);
            const float4 v1 = *(const float4*)(src + g + 4);
            bf16x8 pv;
            pv[0] = f2bf(v0.x); pv[1] = f2bf(v0.y); pv[2] = f2bf(v0.z); pv[3] = f2bf(v0.w);
            pv[4] = f2bf(v1.x); pv[5] = f2bf(v1.y); pv[6] = f2bf(v1.z); pv[7] = f2bf(v1.w);
            const unsigned byteoff = ((unsigned)(row * 512 + k0 * 2)) ^ ((unsigned)((row & 7) << 4));
            *(bf16x8*)(As + byteoff) = pv;
        }
        __syncthreads();   // S1

        // ---- layer 1 MFMA
        f32x4 acc[4][2];
#pragma unroll
        for (int mt = 0; mt < 4; ++mt)
#pragma unroll
            for (int nt = 0; nt < 2; ++nt)
                acc[mt][nt] = (f32x4){0.f, 0.f, 0.f, 0.f};
#pragma unroll
        for (int ks = 0; ks < 8; ++ks) {
            bf16x8 af[4];
#pragma unroll
            for (int mt = 0; mt < 4; ++mt) {
                const int row = mt * 16 + lrow;
                const int k0  = ks * 32 + lk * 8;
                const unsigned byteoff =
                    ((unsigned)(row * 512 + k0 * 2)) ^ ((unsigned)((row & 7) << 4));
                af[mt] = *(const bf16x8*)(As + byteoff);
            }
#pragma unroll
            for (int mt = 0; mt < 4; ++mt)
#pragma unroll
                for (int nt = 0; nt < 2; ++nt)
                    acc[mt][nt] = __builtin_amdgcn_mfma_f32_16x16x32_bf16(
                        af[mt], Bf1[nt][ks], acc[mt][nt], 0, 0, 0);
        }

        // ---- relu + bias -> Bs (bf16, layer-2 A layout: k = n of layer 1)
#pragma unroll
        for (int nt = 0; nt < 2; ++nt) {
            const int n = wave * 32 + nt * 16 + lrow;
#pragma unroll
            for (int mt = 0; mt < 4; ++mt) {
#pragma unroll
                for (int r = 0; r < 4; ++r) {
                    const int row = mt * 16 + lk * 4 + r;
                    const float v = fmaxf(acc[mt][nt][r] + bv1[nt], 0.0f);
                    const unsigned byteoff =
                        ((unsigned)(row * 512 + n * 2)) ^ ((unsigned)((row & 7) << 4));
                    *(short*)(Bs + byteoff) = f2bf(v);
                }
            }
        }
        __syncthreads();   // S2

        // ---- layer 2 MFMA from Bs
#pragma unroll
        for (int mt = 0; mt < 4; ++mt)
#pragma unroll
            for (int nt = 0; nt < 2; ++nt)
                acc[mt][nt] = (f32x4){0.f, 0.f, 0.f, 0.f};
#pragma unroll
        for (int ks = 0; ks < 8; ++ks) {
            bf16x8 af[4];
#pragma unroll
            for (int mt = 0; mt < 4; ++mt) {
                const int row = mt * 16 + lrow;
                const int k0  = ks * 32 + lk * 8;
                const unsigned byteoff =
                    ((unsigned)(row * 512 + k0 * 2)) ^ ((unsigned)((row & 7) << 4));
                af[mt] = *(const bf16x8*)(Bs + byteoff);
            }
#pragma unroll
            for (int mt = 0; mt < 4; ++mt)
#pragma unroll
                for (int nt = 0; nt < 2; ++nt)
                    acc[mt][nt] = __builtin_amdgcn_mfma_f32_16x16x32_bf16(
                        af[mt], Bf2[nt][ks], acc[mt][nt], 0, 0, 0);
        }

        // ---- softshrink + bias, scatter to re/im planes
#pragma unroll
        for (int nt = 0; nt < 2; ++nt) {
            const int n = wave * 32 + nt * 16 + lrow;
            float* dst = (n < 128) ? re : im;
            const int col = blk * 128 + (n & 127);
#pragma unroll
            for (int mt = 0; mt < 4; ++mt) {
#pragma unroll
                for (int r = 0; r < 4; ++r) {
                    const int row = rowbase + mt * 16 + lk * 4 + r;
                    float v = acc[mt][nt][r] + bv2[nt];
                    v = (v > 0.01f) ? v - 0.01f : ((v < -0.01f) ? v + 0.01f : 0.0f);
                    dst[(size_t)row * 512 + col] = v;
                }
            }
        }
        __syncthreads();   // S3: Bs/As reads done before next tile's writes
    }
}

extern "C" void kernel_launch(void* const* d_in, const int* in_sizes, int n_in,
                              void* d_out, int out_size, void* d_ws, size_t ws_size,
                              hipStream_t stream) {
    const float* x  = (const float*)d_in[0];
    const float* w1 = (const float*)d_in[1];
    const float* w2 = (const float*)d_in[2];
    const float* b1 = (const float*)d_in[3];
    const float* b2 = (const float*)d_in[4];

    float* pre = (float*)d_out;   // real plane; ends as the final output
    float* pim = (float*)d_ws;    // imag plane (64 MiB of workspace)

    // forward FFT2 (ortho): 4096 = 64x64 four-step; fft4+scale fused into pass B
    fft_fwd_a<<<2048, 512, 0, stream>>>(x, pre, pim);
    fft_fwd_b<<<2048, 512, 0, stream>>>(pre, pim);

    // fused block-diagonal complex MLP (both layers), in place
    mlp_fused<<<dim3(32768 / (64 * MITER), 4), 512, 0, stream>>>(pre, pim, w1, w2, b1, b2);

    // inverse FFT2 (ortho): fft4_inv+scale fused into pass A, then finish over n
    fft_inv_a<<<2048, 512, 0, stream>>>(pre, pim);
    fft_inv_b<<<2048, 512, 0, stream>>>(pre, pim);
}

// Round 5
// 338.180 us; speedup vs baseline: 5.8793x; 1.0809x over previous
//
#include <hip/hip_runtime.h>
#include <math.h>

#define TWO_PI 6.283185307179586f

typedef __attribute__((ext_vector_type(8))) short bf16x8;
typedef __attribute__((ext_vector_type(4))) float f32x4;

__device__ __forceinline__ short f2bf(float f) {
    unsigned u = __float_as_uint(f);
    unsigned r = (u + 0x7FFFu + ((u >> 16) & 1u)) >> 16;   // RNE
    return (short)r;
}

__device__ __forceinline__ int bitrev6(int s) { return (int)(__brev((unsigned)s) >> 26); }

// ---------------------------------------------------------------------------
// 64-point FFTs across 128 channels in LDS tile [64][128]. 512 threads:
// c = tid&127 (channel), h = tid>>7 (0..3) picks 8 of 32 butterflies/stage.
// ---------------------------------------------------------------------------
__device__ __forceinline__ void fft64_dif(float (*Lre)[128], float (*Lim)[128],
                                          const float* wre, const float* wim,
                                          int c, int h) {
#pragma unroll
    for (int t = 0; t < 6; ++t) {
        const int span = 32 >> t;
        __syncthreads();
#pragma unroll
        for (int jj = 0; jj < 8; ++jj) {
            const int jl = h * 8 + jj;
            const int g  = jl >> (5 - t);
            const int j  = jl & (span - 1);
            const int a  = (g << (6 - t)) + j;
            const int bb = a + span;
            const int m  = j << t;
            const float w_r = wre[m], w_i = wim[m];
            const float ar = Lre[a][c],  ai = Lim[a][c];
            const float br = Lre[bb][c], bi = Lim[bb][c];
            Lre[a][c] = ar + br;
            Lim[a][c] = ai + bi;
            const float dr = ar - br, di = ai - bi;
            Lre[bb][c] = dr * w_r - di * w_i;
            Lim[bb][c] = dr * w_i + di * w_r;
        }
    }
    __syncthreads();
}

__device__ __forceinline__ void fft64_dit_inv(float (*Lre)[128], float (*Lim)[128],
                                              const float* wre, const float* wim,
                                              int c, int h) {
#pragma unroll
    for (int t = 0; t < 6; ++t) {
        const int span = 1 << t;
        __syncthreads();
#pragma unroll
        for (int jj = 0; jj < 8; ++jj) {
            const int jl = h * 8 + jj;
            const int g  = jl >> t;
            const int j  = jl & (span - 1);
            const int a  = (g << (t + 1)) + j;
            const int bb = a + span;
            const int m  = j << (5 - t);
            const float w_r = wre[m], w_i = -wim[m];     // conj -> inverse sign
            const float br = Lre[bb][c], bi = Lim[bb][c];
            const float tr = br * w_r - bi * w_i;
            const float ti = br * w_i + bi * w_r;
            const float ar = Lre[a][c], ai = Lim[a][c];
            Lre[a][c]  = ar + tr;
            Lim[a][c]  = ai + ti;
            Lre[bb][c] = ar - tr;
            Lim[bb][c] = ai - ti;
        }
    }
    __syncthreads();
}

#define DECODE_BCT() \
    const int b  = blockIdx.x >> 8; \
    const int dg = (blockIdx.x >> 2) & 63; \
    const int ct = blockIdx.x & 3;

#define GADDR(slot, blk, f4) \
    (((size_t)(b * 4096 + (slot)) * 512) + (size_t)((blk) * 128 + ct * 32 + (f4) * 4))

#define SETUP_TABLE() \
    if (tid < 32) { \
        float s_, c_; \
        sincosf(TWO_PI * (float)tid / 64.0f, &s_, &c_); \
        wre[tid] = c_; wim[tid] = -s_; \
    }

// ---- forward pass A: FFT over n1 (slots 64*n1+dg), twiddle, x -> pre/pim
extern "C" __global__ void __launch_bounds__(512)
fft_fwd_a(const float* __restrict__ x, float* __restrict__ pre, float* __restrict__ pim) {
    __shared__ __align__(16) float Lre[64][128];
    __shared__ __align__(16) float Lim[64][128];
    __shared__ float wre[32], wim[32];
    const int tid = threadIdx.x;
    SETUP_TABLE();
    DECODE_BCT();   // dg = n2
    for (int idx = tid; idx < 2048; idx += 512) {
        const int n1 = idx >> 5, q = idx & 31, blk = q >> 3, f4 = q & 7;
        const int cl = blk * 32 + f4 * 4;
        const float4 v = *(const float4*)(x + GADDR(n1 * 64 + dg, blk, f4));
        *(float4*)&Lre[n1][cl] = v;
        float4 z; z.x = 0.f; z.y = 0.f; z.z = 0.f; z.w = 0.f;
        *(float4*)&Lim[n1][cl] = z;
    }
    fft64_dif(Lre, Lim, wre, wim, tid & 127, tid >> 7);
    for (int idx = tid; idx < 2048; idx += 512) {
        const int s1 = idx >> 5, q = idx & 31, blk = q >> 3, f4 = q & 7;
        const int cl = blk * 32 + f4 * 4;
        const int k1 = bitrev6(s1);
        float sn, cs;
        sincosf(-(TWO_PI / 4096.0f) * (float)(dg * k1), &sn, &cs);
        const float4 vr = *(const float4*)&Lre[s1][cl];
        const float4 vi = *(const float4*)&Lim[s1][cl];
        float4 orr, oii;
        orr.x = vr.x * cs - vi.x * sn;  oii.x = vr.x * sn + vi.x * cs;
        orr.y = vr.y * cs - vi.y * sn;  oii.y = vr.y * sn + vi.y * cs;
        orr.z = vr.z * cs - vi.z * sn;  oii.z = vr.z * sn + vi.z * cs;
        orr.w = vr.w * cs - vi.w * sn;  oii.w = vr.w * sn + vi.w * cs;
        const size_t g = GADDR(s1 * 64 + dg, blk, f4);
        *(float4*)(pre + g) = orr;
        *(float4*)(pim + g) = oii;
    }
}

// ---- forward pass B: FFT over n2 (contiguous slots) + fused fft4_fwd (x1/128)
extern "C" __global__ void __launch_bounds__(512)
fft_fwd_b(float* __restrict__ pre, float* __restrict__ pim) {
    __shared__ __align__(16) float Lre[64][128];
    __shared__ __align__(16) float Lim[64][128];
    __shared__ float wre[32], wim[32];
    const int tid = threadIdx.x;
    SETUP_TABLE();
    DECODE_BCT();   // dg = s1
    for (int idx = tid; idx < 2048; idx += 512) {
        const int n2 = idx >> 5, q = idx & 31, blk = q >> 3, f4 = q & 7;
        const int cl = blk * 32 + f4 * 4;
        const size_t g = GADDR(dg * 64 + n2, blk, f4);
        *(float4*)&Lre[n2][cl] = *(const float4*)(pre + g);
        *(float4*)&Lim[n2][cl] = *(const float4*)(pim + g);
    }
    fft64_dif(Lre, Lim, wre, wim, tid & 127, tid >> 7);
    for (int idx = tid; idx < 2048; idx += 512) {
        const int s = idx >> 5, dl = idx & 31;
        const float r0 = Lre[s][dl], r1 = Lre[s][dl + 32], r2 = Lre[s][dl + 64], r3 = Lre[s][dl + 96];
        const float m0 = Lim[s][dl], m1 = Lim[s][dl + 32], m2 = Lim[s][dl + 64], m3 = Lim[s][dl + 96];
        const float sc = 1.0f / 128.0f;
        Lre[s][dl]      = (r0 + r1 + r2 + r3) * sc;  Lim[s][dl]      = (m0 + m1 + m2 + m3) * sc;
        Lre[s][dl + 32] = (r0 + m1 - r2 - m3) * sc;  Lim[s][dl + 32] = (m0 - r1 - m2 + r3) * sc;
        Lre[s][dl + 64] = (r0 - r1 + r2 - r3) * sc;  Lim[s][dl + 64] = (m0 - m1 + m2 - m3) * sc;
        Lre[s][dl + 96] = (r0 - m1 - r2 + m3) * sc;  Lim[s][dl + 96] = (m0 + r1 - m2 - r3) * sc;
    }
    __syncthreads();
    for (int idx = tid; idx < 2048; idx += 512) {
        const int s2 = idx >> 5, q = idx & 31, blk = q >> 3, f4 = q & 7;
        const int cl = blk * 32 + f4 * 4;
        const size_t g = GADDR(dg * 64 + s2, blk, f4);
        *(float4*)(pre + g) = *(const float4*)&Lre[s2][cl];
        *(float4*)(pim + g) = *(const float4*)&Lim[s2][cl];
    }
}

// ---- inverse pass A: fused fft4_inv (x1/128), inverse FFT over k2, twiddle
extern "C" __global__ void __launch_bounds__(512)
fft_inv_a(float* __restrict__ pre, float* __restrict__ pim) {
    __shared__ __align__(16) float Lre[64][128];
    __shared__ __align__(16) float Lim[64][128];
    __shared__ float wre[32], wim[32];
    const int tid = threadIdx.x;
    SETUP_TABLE();
    DECODE_BCT();   // dg = s1
    for (int idx = tid; idx < 2048; idx += 512) {
        const int s2 = idx >> 5, q = idx & 31, blk = q >> 3, f4 = q & 7;
        const int cl = blk * 32 + f4 * 4;
        const size_t g = GADDR(dg * 64 + s2, blk, f4);
        *(float4*)&Lre[s2][cl] = *(const float4*)(pre + g);
        *(float4*)&Lim[s2][cl] = *(const float4*)(pim + g);
    }
    __syncthreads();
    for (int idx = tid; idx < 2048; idx += 512) {
        const int s = idx >> 5, dl = idx & 31;
        const float r0 = Lre[s][dl], r1 = Lre[s][dl + 32], r2 = Lre[s][dl + 64], r3 = Lre[s][dl + 96];
        const float m0 = Lim[s][dl], m1 = Lim[s][dl + 32], m2 = Lim[s][dl + 64], m3 = Lim[s][dl + 96];
        const float sc = 1.0f / 128.0f;
        Lre[s][dl]      = (r0 + r1 + r2 + r3) * sc;  Lim[s][dl]      = (m0 + m1 + m2 + m3) * sc;
        Lre[s][dl + 32] = (r0 - m1 - r2 + m3) * sc;  Lim[s][dl + 32] = (m0 + r1 - m2 - r3) * sc;
        Lre[s][dl + 64] = (r0 - r1 + r2 - r3) * sc;  Lim[s][dl + 64] = (m0 - m1 + m2 - m3) * sc;
        Lre[s][dl + 96] = (r0 + m1 - r2 - m3) * sc;  Lim[s][dl + 96] = (m0 - r1 - m2 + r3) * sc;
    }
    fft64_dit_inv(Lre, Lim, wre, wim, tid & 127, tid >> 7);
    for (int idx = tid; idx < 2048; idx += 512) {
        const int n2 = idx >> 5, q = idx & 31, blk = q >> 3, f4 = q & 7;
        const int cl = blk * 32 + f4 * 4;
        const int k1 = bitrev6(dg);
        float sn, cs;
        sincosf((TWO_PI / 4096.0f) * (float)(n2 * k1), &sn, &cs);
        const float4 vr = *(const float4*)&Lre[n2][cl];
        const float4 vi = *(const float4*)&Lim[n2][cl];
        float4 orr, oii;
        orr.x = vr.x * cs - vi.x * sn;  oii.x = vr.x * sn + vi.x * cs;
        orr.y = vr.y * cs - vi.y * sn;  oii.y = vr.y * sn + vi.y * cs;
        orr.z = vr.z * cs - vi.z * sn;  oii.z = vr.z * sn + vi.z * cs;
        orr.w = vr.w * cs - vi.w * sn;  oii.w = vr.w * sn + vi.w * cs;
        const size_t g = GADDR(dg * 64 + n2, blk, f4);
        *(float4*)(pre + g) = orr;
        *(float4*)(pim + g) = oii;
    }
}

// ---- inverse pass B: inverse FFT over k1, write REAL only
extern "C" __global__ void __launch_bounds__(512)
fft_inv_b(float* __restrict__ pre, const float* __restrict__ pim) {
    __shared__ __align__(16) float Lre[64][128];
    __shared__ __align__(16) float Lim[64][128];
    __shared__ float wre[32], wim[32];
    const int tid = threadIdx.x;
    SETUP_TABLE();
    DECODE_BCT();   // dg = n2
    for (int idx = tid; idx < 2048; idx += 512) {
        const int s1 = idx >> 5, q = idx & 31, blk = q >> 3, f4 = q & 7;
        const int cl = blk * 32 + f4 * 4;
        const size_t g = GADDR(s1 * 64 + dg, blk, f4);
        *(float4*)&Lre[s1][cl] = *(const float4*)(pre + g);
        *(float4*)&Lim[s1][cl] = *(const float4*)(pim + g);
    }
    fft64_dit_inv(Lre, Lim, wre, wim, tid & 127, tid >> 7);
    for (int idx = tid; idx < 2048; idx += 512) {
        const int n1 = idx >> 5, q = idx & 31, blk = q >> 3, f4 = q & 7;
        const int cl = blk * 32 + f4 * 4;
        *(float4*)(pre + GADDR(n1 * 64 + dg, blk, f4)) = *(const float4*)&Lre[n1][cl];
    }
}

// ---------------------------------------------------------------------------
// MFMA block-diagonal complex MLP layer, in place (round-3 version: separate
// dispatch per layer — fusing both layers into one kernel regressed 4x due to
// B-fragment register pressure + scalar LDS handoff; inter-layer traffic is
// L3-resident (134 MB working set < 256 MB L3) so fusion saves ~nothing).
// ---------------------------------------------------------------------------
#define MITER 4

template<int LAYER>
__global__ void __launch_bounds__(512)
mlp_mfma(float* __restrict__ re, float* __restrict__ im,
         const float* __restrict__ w, const float* __restrict__ bias) {
    __shared__ __align__(16) char As[64 * 256 * 2];   // 32 KB bf16, swizzled

    const int blk  = blockIdx.y;
    const int tid  = threadIdx.x;
    const int wave = tid >> 6;
    const int lane = tid & 63;
    const int lrow = lane & 15;
    const int lk   = lane >> 4;

    bf16x8 Bf[2][8];
#pragma unroll
    for (int nt = 0; nt < 2; ++nt) {
        const int n = wave * 32 + nt * 16 + lrow;
#pragma unroll
        for (int ks = 0; ks < 8; ++ks) {
            const int kbase = ks * 32 + lk * 8;
            bf16x8 pv;
#pragma unroll
            for (int i = 0; i < 8; ++i) {
                const int k = kbase + i;
                float v;
                if (k < 128) {
                    v = (n < 128) ? w[blk * 16384 + k * 128 + n]
                                  : w[65536 + blk * 16384 + k * 128 + (n - 128)];
                } else {
                    v = (n < 128) ? -w[65536 + blk * 16384 + (k - 128) * 128 + n]
                                  :  w[blk * 16384 + (k - 128) * 128 + (n - 128)];
                }
                pv[i] = f2bf(v);
            }
            Bf[nt][ks] = pv;
        }
    }

    float bv[2];
#pragma unroll
    for (int nt = 0; nt < 2; ++nt) {
        const int n = wave * 32 + nt * 16 + lrow;
        bv[nt] = (n < 128) ? bias[blk * 128 + n] : bias[512 + blk * 128 + (n - 128)];
    }

    for (int t = 0; t < MITER; ++t) {
        const int rowbase = (blockIdx.x * MITER + t) * 64;

        for (int idx = tid; idx < 64 * 32; idx += 512) {
            const int row = idx >> 5;
            const int kg  = idx & 31;
            const int k0  = kg * 8;
            const float* src = (k0 < 128) ? re : im;
            const size_t g = (size_t)(rowbase + row) * 512 + blk * 128 + (k0 & 127);
            const float4 v0 = *(const float4*)(src + g);
            const float4 v1 = *(const float4*)(src + g + 4);
            bf16x8 pv;
            pv[0] = f2bf(v0.x); pv[1] = f2bf(v0.y); pv[2] = f2bf(v0.z); pv[3] = f2bf(v0.w);
            pv[4] = f2bf(v1.x); pv[5] = f2bf(v1.y); pv[6] = f2bf(v1.z); pv[7] = f2bf(v1.w);
            const unsigned byteoff = ((unsigned)(row * 512 + k0 * 2)) ^ ((unsigned)((row & 7) << 4));
            *(bf16x8*)(As + byteoff) = pv;
        }
        __syncthreads();

        f32x4 acc[4][2];
#pragma unroll
        for (int mt = 0; mt < 4; ++mt)
#pragma unroll
            for (int nt = 0; nt < 2; ++nt)
                acc[mt][nt] = (f32x4){0.f, 0.f, 0.f, 0.f};

#pragma unroll
        for (int ks = 0; ks < 8; ++ks) {
            bf16x8 af[4];
#pragma unroll
            for (int mt = 0; mt < 4; ++mt) {
                const int row = mt * 16 + lrow;
                const int k0  = ks * 32 + lk * 8;
                const unsigned byteoff =
                    ((unsigned)(row * 512 + k0 * 2)) ^ ((unsigned)((row & 7) << 4));
                af[mt] = *(const bf16x8*)(As + byteoff);
            }
#pragma unroll
            for (int mt = 0; mt < 4; ++mt)
#pragma unroll
                for (int nt = 0; nt < 2; ++nt)
                    acc[mt][nt] = __builtin_amdgcn_mfma_f32_16x16x32_bf16(
                        af[mt], Bf[nt][ks], acc[mt][nt], 0, 0, 0);
        }
        __syncthreads();

#pragma unroll
        for (int nt = 0; nt < 2; ++nt) {
            const int n = wave * 32 + nt * 16 + lrow;
            float* dst = (n < 128) ? re : im;
            const int col = blk * 128 + (n & 127);
#pragma unroll
            for (int mt = 0; mt < 4; ++mt) {
#pragma unroll
                for (int r = 0; r < 4; ++r) {
                    const int row = rowbase + mt * 16 + lk * 4 + r;
                    float v = acc[mt][nt][r] + bv[nt];
                    if (LAYER == 1) {
                        v = fmaxf(v, 0.0f);
                    } else {
                        v = (v > 0.01f) ? v - 0.01f : ((v < -0.01f) ? v + 0.01f : 0.0f);
                    }
                    dst[(size_t)row * 512 + col] = v;
                }
            }
        }
    }
}

extern "C" void kernel_launch(void* const* d_in, const int* in_sizes, int n_in,
                              void* d_out, int out_size, void* d_ws, size_t ws_size,
                              hipStream_t stream) {
    const float* x  = (const float*)d_in[0];
    const float* w1 = (const float*)d_in[1];
    const float* w2 = (const float*)d_in[2];
    const float* b1 = (const float*)d_in[3];
    const float* b2 = (const float*)d_in[4];

    float* pre = (float*)d_out;   // real plane; ends as the final output
    float* pim = (float*)d_ws;    // imag plane (64 MiB of workspace)

    // forward FFT2 (ortho): 4096 = 64x64 four-step; fft4+scale fused into pass B
    fft_fwd_a<<<2048, 512, 0, stream>>>(x, pre, pim);
    fft_fwd_b<<<2048, 512, 0, stream>>>(pre, pim);

    // block-diagonal complex MLP via MFMA, one dispatch per layer, in place
    mlp_mfma<1><<<dim3(32768 / (64 * MITER), 4), 512, 0, stream>>>(pre, pim, w1, b1);
    mlp_mfma<2><<<dim3(32768 / (64 * MITER), 4), 512, 0, stream>>>(pre, pim, w2, b2);

    // inverse FFT2 (ortho): fft4_inv+scale fused into pass A, then finish over n
    fft_inv_a<<<2048, 512, 0, stream>>>(pre, pim);
    fft_inv_b<<<2048, 512, 0, stream>>>(pre, pim);
}

// Round 6
// 312.117 us; speedup vs baseline: 6.3702x; 1.0835x over previous
//
#include <hip/hip_runtime.h>
#include <math.h>

#define TWO_PI 6.283185307179586f

typedef __attribute__((ext_vector_type(8))) short bf16x8;
typedef __attribute__((ext_vector_type(4))) short bf16x4;
typedef __attribute__((ext_vector_type(4))) float f32x4;

__device__ __forceinline__ short f2bf(float f) {
    unsigned u = __float_as_uint(f);
    unsigned r = (u + 0x7FFFu + ((u >> 16) & 1u)) >> 16;   // RNE
    return (short)r;
}
__device__ __forceinline__ float bf2f(short s) {
    return __uint_as_float(((unsigned)(unsigned short)s) << 16);
}

__device__ __forceinline__ int bitrev6(int s) { return (int)(__brev((unsigned)s) >> 26); }

// ---------------------------------------------------------------------------
// 64-point FFTs across 128 channels in LDS tile [64][128]. 512 threads:
// c = tid&127 (channel), h = tid>>7 (0..3) picks 8 of 32 butterflies/stage.
// ---------------------------------------------------------------------------
__device__ __forceinline__ void fft64_dif(float (*Lre)[128], float (*Lim)[128],
                                          const float* wre, const float* wim,
                                          int c, int h) {
#pragma unroll
    for (int t = 0; t < 6; ++t) {
        const int span = 32 >> t;
        __syncthreads();
#pragma unroll
        for (int jj = 0; jj < 8; ++jj) {
            const int jl = h * 8 + jj;
            const int g  = jl >> (5 - t);
            const int j  = jl & (span - 1);
            const int a  = (g << (6 - t)) + j;
            const int bb = a + span;
            const int m  = j << t;
            const float w_r = wre[m], w_i = wim[m];
            const float ar = Lre[a][c],  ai = Lim[a][c];
            const float br = Lre[bb][c], bi = Lim[bb][c];
            Lre[a][c] = ar + br;
            Lim[a][c] = ai + bi;
            const float dr = ar - br, di = ai - bi;
            Lre[bb][c] = dr * w_r - di * w_i;
            Lim[bb][c] = dr * w_i + di * w_r;
        }
    }
    __syncthreads();
}

__device__ __forceinline__ void fft64_dit_inv(float (*Lre)[128], float (*Lim)[128],
                                              const float* wre, const float* wim,
                                              int c, int h) {
#pragma unroll
    for (int t = 0; t < 6; ++t) {
        const int span = 1 << t;
        __syncthreads();
#pragma unroll
        for (int jj = 0; jj < 8; ++jj) {
            const int jl = h * 8 + jj;
            const int g  = jl >> t;
            const int j  = jl & (span - 1);
            const int a  = (g << (t + 1)) + j;
            const int bb = a + span;
            const int m  = j << (5 - t);
            const float w_r = wre[m], w_i = -wim[m];     // conj -> inverse sign
            const float br = Lre[bb][c], bi = Lim[bb][c];
            const float tr = br * w_r - bi * w_i;
            const float ti = br * w_i + bi * w_r;
            const float ar = Lre[a][c], ai = Lim[a][c];
            Lre[a][c]  = ar + tr;
            Lim[a][c]  = ai + ti;
            Lre[bb][c] = ar - tr;
            Lim[bb][c] = ai - ti;
        }
    }
    __syncthreads();
}

#define DECODE_BCT() \
    const int b  = blockIdx.x >> 8; \
    const int dg = (blockIdx.x >> 2) & 63; \
    const int ct = blockIdx.x & 3;

#define GADDR(slot, blk, f4) \
    (((size_t)(b * 4096 + (slot)) * 512) + (size_t)((blk) * 128 + ct * 32 + (f4) * 4))

#define GADDR8(slot, blk, e8) \
    (((size_t)(b * 4096 + (slot)) * 512) + (size_t)((blk) * 128 + ct * 32 + (e8) * 8))

#define SETUP_TABLE() \
    if (tid < 32) { \
        float s_, c_; \
        sincosf(TWO_PI * (float)tid / 64.0f, &s_, &c_); \
        wre[tid] = c_; wim[tid] = -s_; \
    }

// ---- forward pass A: FFT over n1 (slots 64*n1+dg), twiddle, x fp32 -> z bf16
extern "C" __global__ void __launch_bounds__(512)
fft_fwd_a(const float* __restrict__ x, short* __restrict__ zre, short* __restrict__ zim) {
    __shared__ __align__(16) float Lre[64][128];
    __shared__ __align__(16) float Lim[64][128];
    __shared__ float wre[32], wim[32];
    __shared__ float twr[64], twi[64];
    const int tid = threadIdx.x;
    SETUP_TABLE();
    DECODE_BCT();   // dg = n2
    if (tid >= 64 && tid < 128) {
        const int s1 = tid - 64;
        float sn, cs;
        sincosf(-(TWO_PI / 4096.0f) * (float)(dg * bitrev6(s1)), &sn, &cs);
        twr[s1] = cs; twi[s1] = sn;
    }
    for (int idx = tid; idx < 2048; idx += 512) {
        const int n1 = idx >> 5, q = idx & 31, blk = q >> 3, f4 = q & 7;
        const int cl = blk * 32 + f4 * 4;
        const float4 v = *(const float4*)(x + GADDR(n1 * 64 + dg, blk, f4));
        *(float4*)&Lre[n1][cl] = v;
        float4 z; z.x = 0.f; z.y = 0.f; z.z = 0.f; z.w = 0.f;
        *(float4*)&Lim[n1][cl] = z;
    }
    fft64_dif(Lre, Lim, wre, wim, tid & 127, tid >> 7);
    for (int idx = tid; idx < 2048; idx += 512) {
        const int s1 = idx >> 5, q = idx & 31, blk = q >> 3, f4 = q & 7;
        const int cl = blk * 32 + f4 * 4;
        const float cs = twr[s1], sn = twi[s1];
        const float4 vr = *(const float4*)&Lre[s1][cl];
        const float4 vi = *(const float4*)&Lim[s1][cl];
        bf16x4 pr, pi;
        pr[0] = f2bf(vr.x * cs - vi.x * sn);  pi[0] = f2bf(vr.x * sn + vi.x * cs);
        pr[1] = f2bf(vr.y * cs - vi.y * sn);  pi[1] = f2bf(vr.y * sn + vi.y * cs);
        pr[2] = f2bf(vr.z * cs - vi.z * sn);  pi[2] = f2bf(vr.z * sn + vi.z * cs);
        pr[3] = f2bf(vr.w * cs - vi.w * sn);  pi[3] = f2bf(vr.w * sn + vi.w * cs);
        const size_t g = GADDR(s1 * 64 + dg, blk, f4);
        *(bf16x4*)(zre + g) = pr;
        *(bf16x4*)(zim + g) = pi;
    }
}

// ---- forward pass B: FFT over n2 (contiguous slots) + fused fft4_fwd (x1/128)
extern "C" __global__ void __launch_bounds__(512)
fft_fwd_b(short* __restrict__ zre, short* __restrict__ zim) {
    __shared__ __align__(16) float Lre[64][128];
    __shared__ __align__(16) float Lim[64][128];
    __shared__ float wre[32], wim[32];
    const int tid = threadIdx.x;
    SETUP_TABLE();
    DECODE_BCT();   // dg = s1
    for (int idx = tid; idx < 1024; idx += 512) {
        const int n2 = idx >> 4, q = idx & 15, blk = q >> 2, e8 = q & 3;
        const int cl = blk * 32 + e8 * 8;
        const size_t g = GADDR8(dg * 64 + n2, blk, e8);
        const bf16x8 vr = *(const bf16x8*)(zre + g);
        const bf16x8 vi = *(const bf16x8*)(zim + g);
        float4 a, bq;
        a.x = bf2f(vr[0]); a.y = bf2f(vr[1]); a.z = bf2f(vr[2]); a.w = bf2f(vr[3]);
        bq.x = bf2f(vr[4]); bq.y = bf2f(vr[5]); bq.z = bf2f(vr[6]); bq.w = bf2f(vr[7]);
        *(float4*)&Lre[n2][cl] = a;
        *(float4*)&Lre[n2][cl + 4] = bq;
        a.x = bf2f(vi[0]); a.y = bf2f(vi[1]); a.z = bf2f(vi[2]); a.w = bf2f(vi[3]);
        bq.x = bf2f(vi[4]); bq.y = bf2f(vi[5]); bq.z = bf2f(vi[6]); bq.w = bf2f(vi[7]);
        *(float4*)&Lim[n2][cl] = a;
        *(float4*)&Lim[n2][cl + 4] = bq;
    }
    fft64_dif(Lre, Lim, wre, wim, tid & 127, tid >> 7);
    for (int idx = tid; idx < 2048; idx += 512) {
        const int s = idx >> 5, dl = idx & 31;
        const float r0 = Lre[s][dl], r1 = Lre[s][dl + 32], r2 = Lre[s][dl + 64], r3 = Lre[s][dl + 96];
        const float m0 = Lim[s][dl], m1 = Lim[s][dl + 32], m2 = Lim[s][dl + 64], m3 = Lim[s][dl + 96];
        const float sc = 1.0f / 128.0f;
        Lre[s][dl]      = (r0 + r1 + r2 + r3) * sc;  Lim[s][dl]      = (m0 + m1 + m2 + m3) * sc;
        Lre[s][dl + 32] = (r0 + m1 - r2 - m3) * sc;  Lim[s][dl + 32] = (m0 - r1 - m2 + r3) * sc;
        Lre[s][dl + 64] = (r0 - r1 + r2 - r3) * sc;  Lim[s][dl + 64] = (m0 - m1 + m2 - m3) * sc;
        Lre[s][dl + 96] = (r0 - m1 - r2 + m3) * sc;  Lim[s][dl + 96] = (m0 + r1 - m2 - r3) * sc;
    }
    __syncthreads();
    for (int idx = tid; idx < 1024; idx += 512) {
        const int s2 = idx >> 4, q = idx & 15, blk = q >> 2, e8 = q & 3;
        const int cl = blk * 32 + e8 * 8;
        bf16x8 pr, pi;
#pragma unroll
        for (int i = 0; i < 8; ++i) {
            pr[i] = f2bf(Lre[s2][cl + i]);
            pi[i] = f2bf(Lim[s2][cl + i]);
        }
        const size_t g = GADDR8(dg * 64 + s2, blk, e8);
        *(bf16x8*)(zre + g) = pr;
        *(bf16x8*)(zim + g) = pi;
    }
}

// ---- inverse pass A: fused fft4_inv (x1/128), inverse FFT over k2, twiddle
extern "C" __global__ void __launch_bounds__(512)
fft_inv_a(short* __restrict__ zre, short* __restrict__ zim) {
    __shared__ __align__(16) float Lre[64][128];
    __shared__ __align__(16) float Lim[64][128];
    __shared__ float wre[32], wim[32];
    __shared__ float twr[64], twi[64];
    const int tid = threadIdx.x;
    SETUP_TABLE();
    DECODE_BCT();   // dg = s1
    if (tid >= 64 && tid < 128) {
        const int n2 = tid - 64;
        float sn, cs;
        sincosf((TWO_PI / 4096.0f) * (float)(n2 * bitrev6(dg)), &sn, &cs);
        twr[n2] = cs; twi[n2] = sn;
    }
    for (int idx = tid; idx < 1024; idx += 512) {
        const int s2 = idx >> 4, q = idx & 15, blk = q >> 2, e8 = q & 3;
        const int cl = blk * 32 + e8 * 8;
        const size_t g = GADDR8(dg * 64 + s2, blk, e8);
        const bf16x8 vr = *(const bf16x8*)(zre + g);
        const bf16x8 vi = *(const bf16x8*)(zim + g);
        float4 a, bq;
        a.x = bf2f(vr[0]); a.y = bf2f(vr[1]); a.z = bf2f(vr[2]); a.w = bf2f(vr[3]);
        bq.x = bf2f(vr[4]); bq.y = bf2f(vr[5]); bq.z = bf2f(vr[6]); bq.w = bf2f(vr[7]);
        *(float4*)&Lre[s2][cl] = a;
        *(float4*)&Lre[s2][cl + 4] = bq;
        a.x = bf2f(vi[0]); a.y = bf2f(vi[1]); a.z = bf2f(vi[2]); a.w = bf2f(vi[3]);
        bq.x = bf2f(vi[4]); bq.y = bf2f(vi[5]); bq.z = bf2f(vi[6]); bq.w = bf2f(vi[7]);
        *(float4*)&Lim[s2][cl] = a;
        *(float4*)&Lim[s2][cl + 4] = bq;
    }
    __syncthreads();
    for (int idx = tid; idx < 2048; idx += 512) {
        const int s = idx >> 5, dl = idx & 31;
        const float r0 = Lre[s][dl], r1 = Lre[s][dl + 32], r2 = Lre[s][dl + 64], r3 = Lre[s][dl + 96];
        const float m0 = Lim[s][dl], m1 = Lim[s][dl + 32], m2 = Lim[s][dl + 64], m3 = Lim[s][dl + 96];
        const float sc = 1.0f / 128.0f;
        Lre[s][dl]      = (r0 + r1 + r2 + r3) * sc;  Lim[s][dl]      = (m0 + m1 + m2 + m3) * sc;
        Lre[s][dl + 32] = (r0 - m1 - r2 + m3) * sc;  Lim[s][dl + 32] = (m0 + r1 - m2 - r3) * sc;
        Lre[s][dl + 64] = (r0 - r1 + r2 - r3) * sc;  Lim[s][dl + 64] = (m0 - m1 + m2 - m3) * sc;
        Lre[s][dl + 96] = (r0 + m1 - r2 - m3) * sc;  Lim[s][dl + 96] = (m0 - r1 - m2 + r3) * sc;
    }
    fft64_dit_inv(Lre, Lim, wre, wim, tid & 127, tid >> 7);
    for (int idx = tid; idx < 2048; idx += 512) {
        const int n2 = idx >> 5, q = idx & 31, blk = q >> 3, f4 = q & 7;
        const int cl = blk * 32 + f4 * 4;
        const float cs = twr[n2], sn = twi[n2];
        const float4 vr = *(const float4*)&Lre[n2][cl];
        const float4 vi = *(const float4*)&Lim[n2][cl];
        bf16x4 pr, pi;
        pr[0] = f2bf(vr.x * cs - vi.x * sn);  pi[0] = f2bf(vr.x * sn + vi.x * cs);
        pr[1] = f2bf(vr.y * cs - vi.y * sn);  pi[1] = f2bf(vr.y * sn + vi.y * cs);
        pr[2] = f2bf(vr.z * cs - vi.z * sn);  pi[2] = f2bf(vr.z * sn + vi.z * cs);
        pr[3] = f2bf(vr.w * cs - vi.w * sn);  pi[3] = f2bf(vr.w * sn + vi.w * cs);
        const size_t g = GADDR(dg * 64 + n2, blk, f4);
        *(bf16x4*)(zre + g) = pr;
        *(bf16x4*)(zim + g) = pi;
    }
}

// ---- inverse pass B: inverse FFT over k1, write REAL fp32 into d_out
extern "C" __global__ void __launch_bounds__(512)
fft_inv_b(const short* __restrict__ zre, const short* __restrict__ zim,
          float* __restrict__ out) {
    __shared__ __align__(16) float Lre[64][128];
    __shared__ __align__(16) float Lim[64][128];
    __shared__ float wre[32], wim[32];
    const int tid = threadIdx.x;
    SETUP_TABLE();
    DECODE_BCT();   // dg = n2
    for (int idx = tid; idx < 1024; idx += 512) {
        const int s1 = idx >> 4, q = idx & 15, blk = q >> 2, e8 = q & 3;
        const int cl = blk * 32 + e8 * 8;
        const size_t g = GADDR8(s1 * 64 + dg, blk, e8);
        const bf16x8 vr = *(const bf16x8*)(zre + g);
        const bf16x8 vi = *(const bf16x8*)(zim + g);
        float4 a, bq;
        a.x = bf2f(vr[0]); a.y = bf2f(vr[1]); a.z = bf2f(vr[2]); a.w = bf2f(vr[3]);
        bq.x = bf2f(vr[4]); bq.y = bf2f(vr[5]); bq.z = bf2f(vr[6]); bq.w = bf2f(vr[7]);
        *(float4*)&Lre[s1][cl] = a;
        *(float4*)&Lre[s1][cl + 4] = bq;
        a.x = bf2f(vi[0]); a.y = bf2f(vi[1]); a.z = bf2f(vi[2]); a.w = bf2f(vi[3]);
        bq.x = bf2f(vi[4]); bq.y = bf2f(vi[5]); bq.z = bf2f(vi[6]); bq.w = bf2f(vi[7]);
        *(float4*)&Lim[s1][cl] = a;
        *(float4*)&Lim[s1][cl + 4] = bq;
    }
    fft64_dit_inv(Lre, Lim, wre, wim, tid & 127, tid >> 7);
    for (int idx = tid; idx < 2048; idx += 512) {
        const int n1 = idx >> 5, q = idx & 31, blk = q >> 3, f4 = q & 7;
        const int cl = blk * 32 + f4 * 4;
        *(float4*)(out + GADDR(n1 * 64 + dg, blk, f4)) = *(const float4*)&Lre[n1][cl];
    }
}

// ---------------------------------------------------------------------------
// MFMA block-diagonal complex MLP layer over bf16 planes, in place.
// Staging is now a pure 16B-load -> swizzled 16B LDS write (no conversion).
// ---------------------------------------------------------------------------
#define MITER 4

template<int LAYER>
__global__ void __launch_bounds__(512)
mlp_mfma(short* __restrict__ zre, short* __restrict__ zim,
         const float* __restrict__ w, const float* __restrict__ bias) {
    __shared__ __align__(16) char As[64 * 256 * 2];   // 32 KB bf16, swizzled

    const int blk  = blockIdx.y;
    const int tid  = threadIdx.x;
    const int wave = tid >> 6;
    const int lane = tid & 63;
    const int lrow = lane & 15;
    const int lk   = lane >> 4;

    bf16x8 Bf[2][8];
#pragma unroll
    for (int nt = 0; nt < 2; ++nt) {
        const int n = wave * 32 + nt * 16 + lrow;
#pragma unroll
        for (int ks = 0; ks < 8; ++ks) {
            const int kbase = ks * 32 + lk * 8;
            bf16x8 pv;
#pragma unroll
            for (int i = 0; i < 8; ++i) {
                const int k = kbase + i;
                float v;
                if (k < 128) {
                    v = (n < 128) ? w[blk * 16384 + k * 128 + n]
                                  : w[65536 + blk * 16384 + k * 128 + (n - 128)];
                } else {
                    v = (n < 128) ? -w[65536 + blk * 16384 + (k - 128) * 128 + n]
                                  :  w[blk * 16384 + (k - 128) * 128 + (n - 128)];
                }
                pv[i] = f2bf(v);
            }
            Bf[nt][ks] = pv;
        }
    }

    float bv[2];
#pragma unroll
    for (int nt = 0; nt < 2; ++nt) {
        const int n = wave * 32 + nt * 16 + lrow;
        bv[nt] = (n < 128) ? bias[blk * 128 + n] : bias[512 + blk * 128 + (n - 128)];
    }

    for (int t = 0; t < MITER; ++t) {
        const int rowbase = (blockIdx.x * MITER + t) * 64;

        for (int idx = tid; idx < 64 * 32; idx += 512) {
            const int row = idx >> 5;
            const int kg  = idx & 31;
            const int k0  = kg * 8;
            const short* src = (kg < 16) ? zre : zim;
            const size_t g = (size_t)(rowbase + row) * 512 + blk * 128 + (k0 & 127);
            const bf16x8 pv = *(const bf16x8*)(src + g);
            const unsigned byteoff = ((unsigned)(row * 512 + k0 * 2)) ^ ((unsigned)((row & 7) << 4));
            *(bf16x8*)(As + byteoff) = pv;
        }
        __syncthreads();

        f32x4 acc[4][2];
#pragma unroll
        for (int mt = 0; mt < 4; ++mt)
#pragma unroll
            for (int nt = 0; nt < 2; ++nt)
                acc[mt][nt] = (f32x4){0.f, 0.f, 0.f, 0.f};

#pragma unroll
        for (int ks = 0; ks < 8; ++ks) {
            bf16x8 af[4];
#pragma unroll
            for (int mt = 0; mt < 4; ++mt) {
                const int row = mt * 16 + lrow;
                const int k0  = ks * 32 + lk * 8;
                const unsigned byteoff =
                    ((unsigned)(row * 512 + k0 * 2)) ^ ((unsigned)((row & 7) << 4));
                af[mt] = *(const bf16x8*)(As + byteoff);
            }
#pragma unroll
            for (int mt = 0; mt < 4; ++mt)
#pragma unroll
                for (int nt = 0; nt < 2; ++nt)
                    acc[mt][nt] = __builtin_amdgcn_mfma_f32_16x16x32_bf16(
                        af[mt], Bf[nt][ks], acc[mt][nt], 0, 0, 0);
        }
        __syncthreads();

#pragma unroll
        for (int nt = 0; nt < 2; ++nt) {
            const int n = wave * 32 + nt * 16 + lrow;
            short* dst = (n < 128) ? zre : zim;
            const int col = blk * 128 + (n & 127);
#pragma unroll
            for (int mt = 0; mt < 4; ++mt) {
#pragma unroll
                for (int r = 0; r < 4; ++r) {
                    const int row = rowbase + mt * 16 + lk * 4 + r;
                    float v = acc[mt][nt][r] + bv[nt];
                    if (LAYER == 1) {
                        v = fmaxf(v, 0.0f);
                    } else {
                        v = (v > 0.01f) ? v - 0.01f : ((v < -0.01f) ? v + 0.01f : 0.0f);
                    }
                    dst[(size_t)row * 512 + col] = f2bf(v);
                }
            }
        }
    }
}

extern "C" void kernel_launch(void* const* d_in, const int* in_sizes, int n_in,
                              void* d_out, int out_size, void* d_ws, size_t ws_size,
                              hipStream_t stream) {
    const float* x  = (const float*)d_in[0];
    const float* w1 = (const float*)d_in[1];
    const float* w2 = (const float*)d_in[2];
    const float* b1 = (const float*)d_in[3];
    const float* b2 = (const float*)d_in[4];

    float* out = (float*)d_out;           // final fp32 output (touched only by inv_b)
    short* zre = (short*)d_ws;            // bf16 real plane, 32 MiB
    short* zim = zre + 16777216;          // bf16 imag plane, 32 MiB

    // forward FFT2 (ortho): 4096 = 64x64 four-step; fft4+scale fused into pass B
    fft_fwd_a<<<2048, 512, 0, stream>>>(x, zre, zim);
    fft_fwd_b<<<2048, 512, 0, stream>>>(zre, zim);

    // block-diagonal complex MLP via MFMA, one dispatch per layer, in place
    mlp_mfma<1><<<dim3(32768 / (64 * MITER), 4), 512, 0, stream>>>(zre, zim, w1, b1);
    mlp_mfma<2><<<dim3(32768 / (64 * MITER), 4), 512, 0, stream>>>(zre, zim, w2, b2);

    // inverse FFT2 (ortho): fft4_inv+scale fused into pass A, then finish over n
    fft_inv_a<<<2048, 512, 0, stream>>>(zre, zim);
    fft_inv_b<<<2048, 512, 0, stream>>>(zre, zim, out);
}

// Round 7
// 272.101 us; speedup vs baseline: 7.3070x; 1.1471x over previous
//
#include <hip/hip_runtime.h>
#include <math.h>

#define TWO_PI 6.283185307179586f

typedef __attribute__((ext_vector_type(8))) short bf16x8;
typedef __attribute__((ext_vector_type(4))) short bf16x4;
typedef __attribute__((ext_vector_type(4))) float f32x4;

__device__ __forceinline__ short f2bf(float f) {
    unsigned u = __float_as_uint(f);
    unsigned r = (u + 0x7FFFu + ((u >> 16) & 1u)) >> 16;   // RNE
    return (short)r;
}
__device__ __forceinline__ float bf2f(short s) {
    return __uint_as_float(((unsigned)(unsigned short)s) << 16);
}

__device__ __forceinline__ int bitrev6(int s) { return (int)(__brev((unsigned)s) >> 26); }

// ---------------------------------------------------------------------------
// 64-point FFTs across 128 channels in LDS tile [64][128]. 512 threads:
// c = tid&127 (channel), h = tid>>7 (0..3) picks 8 of 32 butterflies/stage.
// ---------------------------------------------------------------------------
__device__ __forceinline__ void fft64_dif(float (*Lre)[128], float (*Lim)[128],
                                          const float* wre, const float* wim,
                                          int c, int h) {
#pragma unroll
    for (int t = 0; t < 6; ++t) {
        const int span = 32 >> t;
        __syncthreads();
#pragma unroll
        for (int jj = 0; jj < 8; ++jj) {
            const int jl = h * 8 + jj;
            const int g  = jl >> (5 - t);
            const int j  = jl & (span - 1);
            const int a  = (g << (6 - t)) + j;
            const int bb = a + span;
            const int m  = j << t;
            const float w_r = wre[m], w_i = wim[m];
            const float ar = Lre[a][c],  ai = Lim[a][c];
            const float br = Lre[bb][c], bi = Lim[bb][c];
            Lre[a][c] = ar + br;
            Lim[a][c] = ai + bi;
            const float dr = ar - br, di = ai - bi;
            Lre[bb][c] = dr * w_r - di * w_i;
            Lim[bb][c] = dr * w_i + di * w_r;
        }
    }
    __syncthreads();
}

__device__ __forceinline__ void fft64_dit_inv(float (*Lre)[128], float (*Lim)[128],
                                              const float* wre, const float* wim,
                                              int c, int h) {
#pragma unroll
    for (int t = 0; t < 6; ++t) {
        const int span = 1 << t;
        __syncthreads();
#pragma unroll
        for (int jj = 0; jj < 8; ++jj) {
            const int jl = h * 8 + jj;
            const int g  = jl >> t;
            const int j  = jl & (span - 1);
            const int a  = (g << (t + 1)) + j;
            const int bb = a + span;
            const int m  = j << (5 - t);
            const float w_r = wre[m], w_i = -wim[m];     // conj -> inverse sign
            const float br = Lre[bb][c], bi = Lim[bb][c];
            const float tr = br * w_r - bi * w_i;
            const float ti = br * w_i + bi * w_r;
            const float ar = Lre[a][c], ai = Lim[a][c];
            Lre[a][c]  = ar + tr;
            Lim[a][c]  = ai + ti;
            Lre[bb][c] = ar - tr;
            Lim[bb][c] = ai - ti;
        }
    }
    __syncthreads();
}

#define DECODE_BCT() \
    const int b  = blockIdx.x >> 8; \
    const int dg = (blockIdx.x >> 2) & 63; \
    const int ct = blockIdx.x & 3;

#define GADDR(slot, blk, f4) \
    (((size_t)(b * 4096 + (slot)) * 512) + (size_t)((blk) * 128 + ct * 32 + (f4) * 4))

#define GADDR8(slot, blk, e8) \
    (((size_t)(b * 4096 + (slot)) * 512) + (size_t)((blk) * 128 + ct * 32 + (e8) * 8))

#define SETUP_TABLE() \
    if (tid < 32) { \
        float s_, c_; \
        sincosf(TWO_PI * (float)tid / 64.0f, &s_, &c_); \
        wre[tid] = c_; wim[tid] = -s_; \
    }

// ---- forward pass A: FFT over n1 (slots 64*n1+dg), twiddle, x fp32 -> z bf16
extern "C" __global__ void __launch_bounds__(512)
fft_fwd_a(const float* __restrict__ x, short* __restrict__ zre, short* __restrict__ zim) {
    __shared__ __align__(16) float Lre[64][128];
    __shared__ __align__(16) float Lim[64][128];
    __shared__ float wre[32], wim[32];
    __shared__ float twr[64], twi[64];
    const int tid = threadIdx.x;
    SETUP_TABLE();
    DECODE_BCT();   // dg = n2
    if (tid >= 64 && tid < 128) {
        const int s1 = tid - 64;
        float sn, cs;
        sincosf(-(TWO_PI / 4096.0f) * (float)(dg * bitrev6(s1)), &sn, &cs);
        twr[s1] = cs; twi[s1] = sn;
    }
    for (int idx = tid; idx < 2048; idx += 512) {
        const int n1 = idx >> 5, q = idx & 31, blk = q >> 3, f4 = q & 7;
        const int cl = blk * 32 + f4 * 4;
        const float4 v = *(const float4*)(x + GADDR(n1 * 64 + dg, blk, f4));
        *(float4*)&Lre[n1][cl] = v;
        float4 z; z.x = 0.f; z.y = 0.f; z.z = 0.f; z.w = 0.f;
        *(float4*)&Lim[n1][cl] = z;
    }
    fft64_dif(Lre, Lim, wre, wim, tid & 127, tid >> 7);
    for (int idx = tid; idx < 2048; idx += 512) {
        const int s1 = idx >> 5, q = idx & 31, blk = q >> 3, f4 = q & 7;
        const int cl = blk * 32 + f4 * 4;
        const float cs = twr[s1], sn = twi[s1];
        const float4 vr = *(const float4*)&Lre[s1][cl];
        const float4 vi = *(const float4*)&Lim[s1][cl];
        bf16x4 pr, pi;
        pr[0] = f2bf(vr.x * cs - vi.x * sn);  pi[0] = f2bf(vr.x * sn + vi.x * cs);
        pr[1] = f2bf(vr.y * cs - vi.y * sn);  pi[1] = f2bf(vr.y * sn + vi.y * cs);
        pr[2] = f2bf(vr.z * cs - vi.z * sn);  pi[2] = f2bf(vr.z * sn + vi.z * cs);
        pr[3] = f2bf(vr.w * cs - vi.w * sn);  pi[3] = f2bf(vr.w * sn + vi.w * cs);
        const size_t g = GADDR(s1 * 64 + dg, blk, f4);
        *(bf16x4*)(zre + g) = pr;
        *(bf16x4*)(zim + g) = pi;
    }
}

// ---- forward pass B: FFT over n2 (contiguous slots) + fused fft4_fwd (x1/128)
extern "C" __global__ void __launch_bounds__(512)
fft_fwd_b(short* __restrict__ zre, short* __restrict__ zim) {
    __shared__ __align__(16) float Lre[64][128];
    __shared__ __align__(16) float Lim[64][128];
    __shared__ float wre[32], wim[32];
    const int tid = threadIdx.x;
    SETUP_TABLE();
    DECODE_BCT();   // dg = s1
    for (int idx = tid; idx < 1024; idx += 512) {
        const int n2 = idx >> 4, q = idx & 15, blk = q >> 2, e8 = q & 3;
        const int cl = blk * 32 + e8 * 8;
        const size_t g = GADDR8(dg * 64 + n2, blk, e8);
        const bf16x8 vr = *(const bf16x8*)(zre + g);
        const bf16x8 vi = *(const bf16x8*)(zim + g);
        float4 a, bq;
        a.x = bf2f(vr[0]); a.y = bf2f(vr[1]); a.z = bf2f(vr[2]); a.w = bf2f(vr[3]);
        bq.x = bf2f(vr[4]); bq.y = bf2f(vr[5]); bq.z = bf2f(vr[6]); bq.w = bf2f(vr[7]);
        *(float4*)&Lre[n2][cl] = a;
        *(float4*)&Lre[n2][cl + 4] = bq;
        a.x = bf2f(vi[0]); a.y = bf2f(vi[1]); a.z = bf2f(vi[2]); a.w = bf2f(vi[3]);
        bq.x = bf2f(vi[4]); bq.y = bf2f(vi[5]); bq.z = bf2f(vi[6]); bq.w = bf2f(vi[7]);
        *(float4*)&Lim[n2][cl] = a;
        *(float4*)&Lim[n2][cl + 4] = bq;
    }
    fft64_dif(Lre, Lim, wre, wim, tid & 127, tid >> 7);
    for (int idx = tid; idx < 2048; idx += 512) {
        const int s = idx >> 5, dl = idx & 31;
        const float r0 = Lre[s][dl], r1 = Lre[s][dl + 32], r2 = Lre[s][dl + 64], r3 = Lre[s][dl + 96];
        const float m0 = Lim[s][dl], m1 = Lim[s][dl + 32], m2 = Lim[s][dl + 64], m3 = Lim[s][dl + 96];
        const float sc = 1.0f / 128.0f;
        Lre[s][dl]      = (r0 + r1 + r2 + r3) * sc;  Lim[s][dl]      = (m0 + m1 + m2 + m3) * sc;
        Lre[s][dl + 32] = (r0 + m1 - r2 - m3) * sc;  Lim[s][dl + 32] = (m0 - r1 - m2 + r3) * sc;
        Lre[s][dl + 64] = (r0 - r1 + r2 - r3) * sc;  Lim[s][dl + 64] = (m0 - m1 + m2 - m3) * sc;
        Lre[s][dl + 96] = (r0 - m1 - r2 + m3) * sc;  Lim[s][dl + 96] = (m0 + r1 - m2 - r3) * sc;
    }
    __syncthreads();
    for (int idx = tid; idx < 1024; idx += 512) {
        const int s2 = idx >> 4, q = idx & 15, blk = q >> 2, e8 = q & 3;
        const int cl = blk * 32 + e8 * 8;
        bf16x8 pr, pi;
#pragma unroll
        for (int i = 0; i < 8; ++i) {
            pr[i] = f2bf(Lre[s2][cl + i]);
            pi[i] = f2bf(Lim[s2][cl + i]);
        }
        const size_t g = GADDR8(dg * 64 + s2, blk, e8);
        *(bf16x8*)(zre + g) = pr;
        *(bf16x8*)(zim + g) = pi;
    }
}

// ---- inverse pass A: fused fft4_inv (x1/128), inverse FFT over k2, twiddle
extern "C" __global__ void __launch_bounds__(512)
fft_inv_a(short* __restrict__ zre, short* __restrict__ zim) {
    __shared__ __align__(16) float Lre[64][128];
    __shared__ __align__(16) float Lim[64][128];
    __shared__ float wre[32], wim[32];
    __shared__ float twr[64], twi[64];
    const int tid = threadIdx.x;
    SETUP_TABLE();
    DECODE_BCT();   // dg = s1
    if (tid >= 64 && tid < 128) {
        const int n2 = tid - 64;
        float sn, cs;
        sincosf((TWO_PI / 4096.0f) * (float)(n2 * bitrev6(dg)), &sn, &cs);
        twr[n2] = cs; twi[n2] = sn;
    }
    for (int idx = tid; idx < 1024; idx += 512) {
        const int s2 = idx >> 4, q = idx & 15, blk = q >> 2, e8 = q & 3;
        const int cl = blk * 32 + e8 * 8;
        const size_t g = GADDR8(dg * 64 + s2, blk, e8);
        const bf16x8 vr = *(const bf16x8*)(zre + g);
        const bf16x8 vi = *(const bf16x8*)(zim + g);
        float4 a, bq;
        a.x = bf2f(vr[0]); a.y = bf2f(vr[1]); a.z = bf2f(vr[2]); a.w = bf2f(vr[3]);
        bq.x = bf2f(vr[4]); bq.y = bf2f(vr[5]); bq.z = bf2f(vr[6]); bq.w = bf2f(vr[7]);
        *(float4*)&Lre[s2][cl] = a;
        *(float4*)&Lre[s2][cl + 4] = bq;
        a.x = bf2f(vi[0]); a.y = bf2f(vi[1]); a.z = bf2f(vi[2]); a.w = bf2f(vi[3]);
        bq.x = bf2f(vi[4]); bq.y = bf2f(vi[5]); bq.z = bf2f(vi[6]); bq.w = bf2f(vi[7]);
        *(float4*)&Lim[s2][cl] = a;
        *(float4*)&Lim[s2][cl + 4] = bq;
    }
    __syncthreads();
    for (int idx = tid; idx < 2048; idx += 512) {
        const int s = idx >> 5, dl = idx & 31;
        const float r0 = Lre[s][dl], r1 = Lre[s][dl + 32], r2 = Lre[s][dl + 64], r3 = Lre[s][dl + 96];
        const float m0 = Lim[s][dl], m1 = Lim[s][dl + 32], m2 = Lim[s][dl + 64], m3 = Lim[s][dl + 96];
        const float sc = 1.0f / 128.0f;
        Lre[s][dl]      = (r0 + r1 + r2 + r3) * sc;  Lim[s][dl]      = (m0 + m1 + m2 + m3) * sc;
        Lre[s][dl + 32] = (r0 - m1 - r2 + m3) * sc;  Lim[s][dl + 32] = (m0 + r1 - m2 - r3) * sc;
        Lre[s][dl + 64] = (r0 - r1 + r2 - r3) * sc;  Lim[s][dl + 64] = (m0 - m1 + m2 - m3) * sc;
        Lre[s][dl + 96] = (r0 + m1 - r2 - m3) * sc;  Lim[s][dl + 96] = (m0 - r1 - m2 + r3) * sc;
    }
    fft64_dit_inv(Lre, Lim, wre, wim, tid & 127, tid >> 7);
    for (int idx = tid; idx < 2048; idx += 512) {
        const int n2 = idx >> 5, q = idx & 31, blk = q >> 3, f4 = q & 7;
        const int cl = blk * 32 + f4 * 4;
        const float cs = twr[n2], sn = twi[n2];
        const float4 vr = *(const float4*)&Lre[n2][cl];
        const float4 vi = *(const float4*)&Lim[n2][cl];
        bf16x4 pr, pi;
        pr[0] = f2bf(vr.x * cs - vi.x * sn);  pi[0] = f2bf(vr.x * sn + vi.x * cs);
        pr[1] = f2bf(vr.y * cs - vi.y * sn);  pi[1] = f2bf(vr.y * sn + vi.y * cs);
        pr[2] = f2bf(vr.z * cs - vi.z * sn);  pi[2] = f2bf(vr.z * sn + vi.z * cs);
        pr[3] = f2bf(vr.w * cs - vi.w * sn);  pi[3] = f2bf(vr.w * sn + vi.w * cs);
        const size_t g = GADDR(dg * 64 + n2, blk, f4);
        *(bf16x4*)(zre + g) = pr;
        *(bf16x4*)(zim + g) = pi;
    }
}

// ---- inverse pass B: inverse FFT over k1, write REAL fp32 into d_out
extern "C" __global__ void __launch_bounds__(512)
fft_inv_b(const short* __restrict__ zre, const short* __restrict__ zim,
          float* __restrict__ out) {
    __shared__ __align__(16) float Lre[64][128];
    __shared__ __align__(16) float Lim[64][128];
    __shared__ float wre[32], wim[32];
    const int tid = threadIdx.x;
    SETUP_TABLE();
    DECODE_BCT();   // dg = n2
    for (int idx = tid; idx < 1024; idx += 512) {
        const int s1 = idx >> 4, q = idx & 15, blk = q >> 2, e8 = q & 3;
        const int cl = blk * 32 + e8 * 8;
        const size_t g = GADDR8(s1 * 64 + dg, blk, e8);
        const bf16x8 vr = *(const bf16x8*)(zre + g);
        const bf16x8 vi = *(const bf16x8*)(zim + g);
        float4 a, bq;
        a.x = bf2f(vr[0]); a.y = bf2f(vr[1]); a.z = bf2f(vr[2]); a.w = bf2f(vr[3]);
        bq.x = bf2f(vr[4]); bq.y = bf2f(vr[5]); bq.z = bf2f(vr[6]); bq.w = bf2f(vr[7]);
        *(float4*)&Lre[s1][cl] = a;
        *(float4*)&Lre[s1][cl + 4] = bq;
        a.x = bf2f(vi[0]); a.y = bf2f(vi[1]); a.z = bf2f(vi[2]); a.w = bf2f(vi[3]);
        bq.x = bf2f(vi[4]); bq.y = bf2f(vi[5]); bq.z = bf2f(vi[6]); bq.w = bf2f(vi[7]);
        *(float4*)&Lim[s1][cl] = a;
        *(float4*)&Lim[s1][cl + 4] = bq;
    }
    fft64_dit_inv(Lre, Lim, wre, wim, tid & 127, tid >> 7);
    for (int idx = tid; idx < 2048; idx += 512) {
        const int n1 = idx >> 5, q = idx & 31, blk = q >> 3, f4 = q & 7;
        const int cl = blk * 32 + f4 * 4;
        *(float4*)(out + GADDR(n1 * 64 + dg, blk, f4)) = *(const float4*)&Lre[n1][cl];
    }
}

// ---------------------------------------------------------------------------
// Weight prep: fold complex 2x2 structure into W_big bf16 [L][blk][n][k],
// stored in d_out (fully overwritten later by fft_inv_b).
// ---------------------------------------------------------------------------
extern "C" __global__ void __launch_bounds__(256)
wprep(const float* __restrict__ w1, const float* __restrict__ w2,
      short* __restrict__ wb) {
    const int i4  = blockIdx.x * 256 + threadIdx.x;   // 0..131071 (quads of k)
    const int k0  = (i4 & 63) * 4;
    const int n   = (i4 >> 6) & 255;
    const int blk = (i4 >> 14) & 3;
    const int L   = i4 >> 16;
    const float* w = L ? w2 : w1;
    bf16x4 pv;
#pragma unroll
    for (int j = 0; j < 4; ++j) {
        const int k = k0 + j;
        float v;
        if (k < 128) {
            v = (n < 128) ? w[blk * 16384 + k * 128 + n]
                          : w[65536 + blk * 16384 + k * 128 + (n - 128)];
        } else {
            v = (n < 128) ? -w[65536 + blk * 16384 + (k - 128) * 128 + n]
                          :  w[blk * 16384 + (k - 128) * 128 + (n - 128)];
        }
        pv[j] = f2bf(v);
    }
    *(bf16x4*)(wb + (size_t)i4 * 4) = pv;
}

// ---------------------------------------------------------------------------
// MFMA block-diagonal complex MLP layer over bf16 planes, in place.
// - B fragments: 16B vector loads from prepped W_big (L2-hot).
// - A staging: global_load_lds 16B direct-to-LDS, swizzle applied to the
//   GLOBAL source address (LDS dest linear in lane order).
// - Double-buffered LDS, 2-phase pipeline: issue next tile's loads before
//   computing current tile.
// ---------------------------------------------------------------------------
#define MITER 4

__device__ __forceinline__ void stage_tile(const short* __restrict__ zre,
                                           const short* __restrict__ zim,
                                           char* Abuf, int rowbase, int blk,
                                           int wave, int lane) {
#pragma unroll
    for (int it = 0; it < 4; ++it) {
        const int chunk = wave * 256 + it * 64 + lane;   // 16B chunk id, 0..2047
        const int row   = chunk >> 5;
        const unsigned kbyte = ((unsigned)((chunk & 31) << 4)) ^ ((unsigned)((row & 7) << 4));
        const int k0 = (int)(kbyte >> 1);                // element k, multiple of 8
        const short* src = (k0 < 128) ? zre : zim;
        const size_t g = (size_t)(rowbase + row) * 512 + blk * 128 + (k0 & 127);
        unsigned* lp = (unsigned*)(Abuf + (wave * 4096 + it * 1024));  // wave-uniform
        __builtin_amdgcn_global_load_lds((const unsigned*)(src + g), lp, 16, 0, 0);
    }
}

template<int LAYER>
__global__ void __launch_bounds__(512)
mlp_mfma(short* __restrict__ zre, short* __restrict__ zim,
         const short* __restrict__ wb, const float* __restrict__ bias) {
    __shared__ __align__(16) char As[2][64 * 256 * 2];   // 2 x 32 KB bf16, swizzled

    const int blk  = blockIdx.y;
    const int tid  = threadIdx.x;
    const int wave = tid >> 6;
    const int lane = tid & 63;
    const int lrow = lane & 15;
    const int lk   = lane >> 4;

    // ---- B fragments: one bf16x8 load each from W_big[blk][n][k]
    bf16x8 Bf[2][8];
#pragma unroll
    for (int nt = 0; nt < 2; ++nt) {
        const int n = wave * 32 + nt * 16 + lrow;
#pragma unroll
        for (int ks = 0; ks < 8; ++ks) {
            Bf[nt][ks] = *(const bf16x8*)(wb + ((size_t)(blk * 256 + n) * 256 + ks * 32 + lk * 8));
        }
    }

    float bv[2];
#pragma unroll
    for (int nt = 0; nt < 2; ++nt) {
        const int n = wave * 32 + nt * 16 + lrow;
        bv[nt] = (n < 128) ? bias[blk * 128 + n] : bias[512 + blk * 128 + (n - 128)];
    }

    // ---- prologue: stage tile 0 into buffer 0
    stage_tile(zre, zim, As[0], blockIdx.x * MITER * 64, blk, wave, lane);

    for (int t = 0; t < MITER; ++t) {
        __syncthreads();   // drains vmcnt: buf[t&1] staged; prior compute done

        if (t + 1 < MITER)
            stage_tile(zre, zim, As[(t + 1) & 1],
                       (blockIdx.x * MITER + t + 1) * 64, blk, wave, lane);

        const char* Ab = As[t & 1];
        const int rowbase = (blockIdx.x * MITER + t) * 64;

        f32x4 acc[4][2];
#pragma unroll
        for (int mt = 0; mt < 4; ++mt)
#pragma unroll
            for (int nt = 0; nt < 2; ++nt)
                acc[mt][nt] = (f32x4){0.f, 0.f, 0.f, 0.f};

#pragma unroll
        for (int ks = 0; ks < 8; ++ks) {
            bf16x8 af[4];
#pragma unroll
            for (int mt = 0; mt < 4; ++mt) {
                const int row = mt * 16 + lrow;
                const int k0  = ks * 32 + lk * 8;
                const unsigned byteoff =
                    ((unsigned)(row * 512 + k0 * 2)) ^ ((unsigned)((row & 7) << 4));
                af[mt] = *(const bf16x8*)(Ab + byteoff);
            }
#pragma unroll
            for (int mt = 0; mt < 4; ++mt)
#pragma unroll
                for (int nt = 0; nt < 2; ++nt)
                    acc[mt][nt] = __builtin_amdgcn_mfma_f32_16x16x32_bf16(
                        af[mt], Bf[nt][ks], acc[mt][nt], 0, 0, 0);
        }

#pragma unroll
        for (int nt = 0; nt < 2; ++nt) {
            const int n = wave * 32 + nt * 16 + lrow;
            short* dst = (n < 128) ? zre : zim;
            const int col = blk * 128 + (n & 127);
#pragma unroll
            for (int mt = 0; mt < 4; ++mt) {
#pragma unroll
                for (int r = 0; r < 4; ++r) {
                    const int row = rowbase + mt * 16 + lk * 4 + r;
                    float v = acc[mt][nt][r] + bv[nt];
                    if (LAYER == 1) {
                        v = fmaxf(v, 0.0f);
                    } else {
                        v = (v > 0.01f) ? v - 0.01f : ((v < -0.01f) ? v + 0.01f : 0.0f);
                    }
                    dst[(size_t)row * 512 + col] = f2bf(v);
                }
            }
        }
    }
}

extern "C" void kernel_launch(void* const* d_in, const int* in_sizes, int n_in,
                              void* d_out, int out_size, void* d_ws, size_t ws_size,
                              hipStream_t stream) {
    const float* x  = (const float*)d_in[0];
    const float* w1 = (const float*)d_in[1];
    const float* w2 = (const float*)d_in[2];
    const float* b1 = (const float*)d_in[3];
    const float* b2 = (const float*)d_in[4];

    float* out = (float*)d_out;           // final fp32 output (fully written by inv_b)
    short* zre = (short*)d_ws;            // bf16 real plane, 32 MiB
    short* zim = zre + 16777216;          // bf16 imag plane, 32 MiB
    short* wb  = (short*)d_out;           // 1 MiB W_big scratch inside d_out
    const size_t WB_L = 4ull * 256 * 256; // per-layer elements

    // weight prep (d_out scratch; overwritten by inv_b at the end)
    wprep<<<512, 256, 0, stream>>>(w1, w2, wb);

    // forward FFT2 (ortho): 4096 = 64x64 four-step; fft4+scale fused into pass B
    fft_fwd_a<<<2048, 512, 0, stream>>>(x, zre, zim);
    fft_fwd_b<<<2048, 512, 0, stream>>>(zre, zim);

    // block-diagonal complex MLP via MFMA, one dispatch per layer, in place
    mlp_mfma<1><<<dim3(32768 / (64 * MITER), 4), 512, 0, stream>>>(zre, zim, wb, b1);
    mlp_mfma<2><<<dim3(32768 / (64 * MITER), 4), 512, 0, stream>>>(zre, zim, wb + WB_L, b2);

    // inverse FFT2 (ortho): fft4_inv+scale fused into pass A, then finish over n
    fft_inv_a<<<2048, 512, 0, stream>>>(zre, zim);
    fft_inv_b<<<2048, 512, 0, stream>>>(zre, zim, out);
}

// Round 8
// 266.359 us; speedup vs baseline: 7.4646x; 1.0216x over previous
//
#include <hip/hip_runtime.h>
#include <math.h>

#define TWO_PI 6.283185307179586f

typedef __attribute__((ext_vector_type(8))) short bf16x8;
typedef __attribute__((ext_vector_type(4))) short bf16x4;
typedef __attribute__((ext_vector_type(4))) float f32x4;

__device__ __forceinline__ short f2bf(float f) {
    unsigned u = __float_as_uint(f);
    unsigned r = (u + 0x7FFFu + ((u >> 16) & 1u)) >> 16;   // RNE
    return (short)r;
}
__device__ __forceinline__ float bf2f(short s) {
    return __uint_as_float(((unsigned)(unsigned short)s) << 16);
}

__device__ __forceinline__ int bitrev6(int s) { return (int)(__brev((unsigned)s) >> 26); }

__device__ __forceinline__ void cmulw(float& xr, float& xi, float wr, float wi) {
    const float tr = xr * wr - xi * wi;
    xi = xr * wi + xi * wr;
    xr = tr;
}

// ---------------------------------------------------------------------------
// Register-resident 64-point FFT, radix-4, 3 stages, fully unrolled.
// Forward: DIF, natural in -> digit-reversed out, sign e^{-i}.
// Inverse: exact stage-by-stage reversal (DIT), digit-reversed in -> natural
// out, conj twiddles, unscaled (x64 overall; absorbed by the 1/128 factors).
// wtr/wti: W64^m = (cos, -sin)(2pi m/64), m in [0,48).
// ---------------------------------------------------------------------------
__device__ __forceinline__ void fft64_regs_fwd(float* cr, float* ci,
                                               const float* wtr, const float* wti) {
#pragma unroll
    for (int s = 0; s < 3; ++s) {
        const int L = 64 >> (2 * s), q = L >> 2, G = 1 << (2 * s), tw = 1 << (2 * s);
#pragma unroll
        for (int g = 0; g < G; ++g) {
#pragma unroll
            for (int j = 0; j < q; ++j) {
                const int i0 = g * L + j, i1 = i0 + q, i2 = i1 + q, i3 = i2 + q;
                const float t0r = cr[i0] + cr[i2], t0i = ci[i0] + ci[i2];
                const float t2r = cr[i0] - cr[i2], t2i = ci[i0] - ci[i2];
                const float t1r = cr[i1] + cr[i3], t1i = ci[i1] + ci[i3];
                const float dr  = cr[i1] - cr[i3], di  = ci[i1] - ci[i3];
                const float t3r = di, t3i = -dr;                 // -i*(a1-a3)
                cr[i0] = t0r + t1r;  ci[i0] = t0i + t1i;
                float y1r = t2r + t3r, y1i = t2i + t3i;
                float y2r = t0r - t1r, y2i = t0i - t1i;
                float y3r = t2r - t3r, y3i = t2i - t3i;
                const int m = j * tw;
                if (m) {
                    cmulw(y1r, y1i, wtr[m], wti[m]);
                    cmulw(y2r, y2i, wtr[2 * m], wti[2 * m]);
                    cmulw(y3r, y3i, wtr[3 * m], wti[3 * m]);
                }
                cr[i1] = y1r; ci[i1] = y1i;
                cr[i2] = y2r; ci[i2] = y2i;
                cr[i3] = y3r; ci[i3] = y3i;
            }
        }
    }
}

__device__ __forceinline__ void fft64_regs_inv(float* cr, float* ci,
                                               const float* wtr, const float* wti) {
#pragma unroll
    for (int s = 2; s >= 0; --s) {
        const int L = 64 >> (2 * s), q = L >> 2, G = 1 << (2 * s), tw = 1 << (2 * s);
#pragma unroll
        for (int g = 0; g < G; ++g) {
#pragma unroll
            for (int j = 0; j < q; ++j) {
                const int i0 = g * L + j, i1 = i0 + q, i2 = i1 + q, i3 = i2 + q;
                float b1r = cr[i1], b1i = ci[i1];
                float b2r = cr[i2], b2i = ci[i2];
                float b3r = cr[i3], b3i = ci[i3];
                const int m = j * tw;
                if (m) {
                    cmulw(b1r, b1i, wtr[m], -wti[m]);            // conj
                    cmulw(b2r, b2i, wtr[2 * m], -wti[2 * m]);
                    cmulw(b3r, b3i, wtr[3 * m], -wti[3 * m]);
                }
                const float u0r = cr[i0] + b2r, u0i = ci[i0] + b2i;
                const float u1r = cr[i0] - b2r, u1i = ci[i0] - b2i;
                const float u2r = b1r + b3r,    u2i = b1i + b3i;
                const float dr  = b1r - b3r,    di  = b1i - b3i;
                const float u3r = -di, u3i = dr;                 // +i*(b1-b3)
                cr[i0] = u0r + u2r; ci[i0] = u0i + u2i;
                cr[i1] = u1r + u3r; ci[i1] = u1i + u3i;
                cr[i2] = u0r - u2r; ci[i2] = u0i - u2i;
                cr[i3] = u1r - u3r; ci[i3] = u1i - u3i;
            }
        }
    }
}

// ---------------------------------------------------------------------------
// LDS 64-pt FFT helpers for the outer passes (unchanged, proven).
// ---------------------------------------------------------------------------
__device__ __forceinline__ void fft64_dif(float (*Lre)[128], float (*Lim)[128],
                                          const float* wre, const float* wim,
                                          int c, int h) {
#pragma unroll
    for (int t = 0; t < 6; ++t) {
        const int span = 32 >> t;
        __syncthreads();
#pragma unroll
        for (int jj = 0; jj < 8; ++jj) {
            const int jl = h * 8 + jj;
            const int g  = jl >> (5 - t);
            const int j  = jl & (span - 1);
            const int a  = (g << (6 - t)) + j;
            const int bb = a + span;
            const int m  = j << t;
            const float w_r = wre[m], w_i = wim[m];
            const float ar = Lre[a][c],  ai = Lim[a][c];
            const float br = Lre[bb][c], bi = Lim[bb][c];
            Lre[a][c] = ar + br;
            Lim[a][c] = ai + bi;
            const float dr = ar - br, di = ai - bi;
            Lre[bb][c] = dr * w_r - di * w_i;
            Lim[bb][c] = dr * w_i + di * w_r;
        }
    }
    __syncthreads();
}

__device__ __forceinline__ void fft64_dit_inv(float (*Lre)[128], float (*Lim)[128],
                                              const float* wre, const float* wim,
                                              int c, int h) {
#pragma unroll
    for (int t = 0; t < 6; ++t) {
        const int span = 1 << t;
        __syncthreads();
#pragma unroll
        for (int jj = 0; jj < 8; ++jj) {
            const int jl = h * 8 + jj;
            const int g  = jl >> t;
            const int j  = jl & (span - 1);
            const int a  = (g << (t + 1)) + j;
            const int bb = a + span;
            const int m  = j << (5 - t);
            const float w_r = wre[m], w_i = -wim[m];
            const float br = Lre[bb][c], bi = Lim[bb][c];
            const float tr = br * w_r - bi * w_i;
            const float ti = br * w_i + bi * w_r;
            const float ar = Lre[a][c], ai = Lim[a][c];
            Lre[a][c]  = ar + tr;
            Lim[a][c]  = ai + ti;
            Lre[bb][c] = ar - tr;
            Lim[bb][c] = ai - ti;
        }
    }
    __syncthreads();
}

#define DECODE_BCT() \
    const int b  = blockIdx.x >> 8; \
    const int dg = (blockIdx.x >> 2) & 63; \
    const int ct = blockIdx.x & 3;

#define GADDR(slot, blk, f4) \
    (((size_t)(b * 4096 + (slot)) * 512) + (size_t)((blk) * 128 + ct * 32 + (f4) * 4))

#define GADDR8(slot, blk, e8) \
    (((size_t)(b * 4096 + (slot)) * 512) + (size_t)((blk) * 128 + ct * 32 + (e8) * 8))

#define SETUP_TABLE() \
    if (tid < 32) { \
        float s_, c_; \
        sincosf(TWO_PI * (float)tid / 64.0f, &s_, &c_); \
        wre[tid] = c_; wim[tid] = -s_; \
    }

// ---- forward pass A: FFT over n1 (slots 64*n1+dg), twiddle, x fp32 -> z bf16
extern "C" __global__ void __launch_bounds__(512)
fft_fwd_a(const float* __restrict__ x, short* __restrict__ zre, short* __restrict__ zim) {
    __shared__ __align__(16) float Lre[64][128];
    __shared__ __align__(16) float Lim[64][128];
    __shared__ float wre[32], wim[32];
    __shared__ float twr[64], twi[64];
    const int tid = threadIdx.x;
    SETUP_TABLE();
    DECODE_BCT();   // dg = n2
    if (tid >= 64 && tid < 128) {
        const int s1 = tid - 64;
        float sn, cs;
        sincosf(-(TWO_PI / 4096.0f) * (float)(dg * bitrev6(s1)), &sn, &cs);
        twr[s1] = cs; twi[s1] = sn;
    }
    for (int idx = tid; idx < 2048; idx += 512) {
        const int n1 = idx >> 5, q = idx & 31, blk = q >> 3, f4 = q & 7;
        const int cl = blk * 32 + f4 * 4;
        const float4 v = *(const float4*)(x + GADDR(n1 * 64 + dg, blk, f4));
        *(float4*)&Lre[n1][cl] = v;
        float4 z; z.x = 0.f; z.y = 0.f; z.z = 0.f; z.w = 0.f;
        *(float4*)&Lim[n1][cl] = z;
    }
    fft64_dif(Lre, Lim, wre, wim, tid & 127, tid >> 7);
    for (int idx = tid; idx < 2048; idx += 512) {
        const int s1 = idx >> 5, q = idx & 31, blk = q >> 3, f4 = q & 7;
        const int cl = blk * 32 + f4 * 4;
        const float cs = twr[s1], sn = twi[s1];
        const float4 vr = *(const float4*)&Lre[s1][cl];
        const float4 vi = *(const float4*)&Lim[s1][cl];
        bf16x4 pr, pi;
        pr[0] = f2bf(vr.x * cs - vi.x * sn);  pi[0] = f2bf(vr.x * sn + vi.x * cs);
        pr[1] = f2bf(vr.y * cs - vi.y * sn);  pi[1] = f2bf(vr.y * sn + vi.y * cs);
        pr[2] = f2bf(vr.z * cs - vi.z * sn);  pi[2] = f2bf(vr.z * sn + vi.z * cs);
        pr[3] = f2bf(vr.w * cs - vi.w * sn);  pi[3] = f2bf(vr.w * sn + vi.w * cs);
        const size_t g = GADDR(s1 * 64 + dg, blk, f4);
        *(bf16x4*)(zre + g) = pr;
        *(bf16x4*)(zim + g) = pi;
    }
}

// ---- inverse pass B: inverse FFT over k1, write REAL fp32 into d_out
extern "C" __global__ void __launch_bounds__(512)
fft_inv_b(const short* __restrict__ zre, const short* __restrict__ zim,
          float* __restrict__ out) {
    __shared__ __align__(16) float Lre[64][128];
    __shared__ __align__(16) float Lim[64][128];
    __shared__ float wre[32], wim[32];
    const int tid = threadIdx.x;
    SETUP_TABLE();
    DECODE_BCT();   // dg = n2
    for (int idx = tid; idx < 1024; idx += 512) {
        const int s1 = idx >> 4, q = idx & 15, blk = q >> 2, e8 = q & 3;
        const int cl = blk * 32 + e8 * 8;
        const size_t g = GADDR8(s1 * 64 + dg, blk, e8);
        const bf16x8 vr = *(const bf16x8*)(zre + g);
        const bf16x8 vi = *(const bf16x8*)(zim + g);
        float4 a, bq;
        a.x = bf2f(vr[0]); a.y = bf2f(vr[1]); a.z = bf2f(vr[2]); a.w = bf2f(vr[3]);
        bq.x = bf2f(vr[4]); bq.y = bf2f(vr[5]); bq.z = bf2f(vr[6]); bq.w = bf2f(vr[7]);
        *(float4*)&Lre[s1][cl] = a;
        *(float4*)&Lre[s1][cl + 4] = bq;
        a.x = bf2f(vi[0]); a.y = bf2f(vi[1]); a.z = bf2f(vi[2]); a.w = bf2f(vi[3]);
        bq.x = bf2f(vi[4]); bq.y = bf2f(vi[5]); bq.z = bf2f(vi[6]); bq.w = bf2f(vi[7]);
        *(float4*)&Lim[s1][cl] = a;
        *(float4*)&Lim[s1][cl + 4] = bq;
    }
    fft64_dit_inv(Lre, Lim, wre, wim, tid & 127, tid >> 7);
    for (int idx = tid; idx < 2048; idx += 512) {
        const int n1 = idx >> 5, q = idx & 31, blk = q >> 3, f4 = q & 7;
        const int cl = blk * 32 + f4 * 4;
        *(float4*)(out + GADDR(n1 * 64 + dg, blk, f4)) = *(const float4*)&Lre[n1][cl];
    }
}

// ---------------------------------------------------------------------------
// Weight prep: fold complex 2x2 into W_big bf16 [L][blk][n][k], in d_out.
// ---------------------------------------------------------------------------
extern "C" __global__ void __launch_bounds__(256)
wprep(const float* __restrict__ w1, const float* __restrict__ w2,
      short* __restrict__ wb) {
    const int i4  = blockIdx.x * 256 + threadIdx.x;
    const int k0  = (i4 & 63) * 4;
    const int n   = (i4 >> 6) & 255;
    const int blk = (i4 >> 14) & 3;
    const int L   = i4 >> 16;
    const float* w = L ? w2 : w1;
    bf16x4 pv;
#pragma unroll
    for (int j = 0; j < 4; ++j) {
        const int k = k0 + j;
        float v;
        if (k < 128) {
            v = (n < 128) ? w[blk * 16384 + k * 128 + n]
                          : w[65536 + blk * 16384 + k * 128 + (n - 128)];
        } else {
            v = (n < 128) ? -w[65536 + blk * 16384 + (k - 128) * 128 + n]
                          :  w[blk * 16384 + (k - 128) * 128 + (n - 128)];
        }
        pv[j] = f2bf(v);
    }
    *(bf16x4*)(wb + (size_t)i4 * 4) = pv;
}

// ---------------------------------------------------------------------------
// Fused middle kernel: per contiguous 64-slot x 512-ch tile (b, s1):
//   P1 fwd 64-pt FFT over n2 (registers, radix-4)
//   P2 fft4 across blocks + 1/128
//   P3 MLP layer1(relu) -> A2 -> layer2(softshrink), MFMA, per blk, 32-row halves
//   P5a inverse fft4 + 1/128 ; P5b inverse FFT (registers) + output twiddle
// Z LDS tile is bf16, rows XOR-swizzled with ((slot&7)<<4) on byte offsets.
// ---------------------------------------------------------------------------
extern "C" __global__ void __launch_bounds__(512, 2)
mid_fused(short* __restrict__ zre, short* __restrict__ zim,
          const short* __restrict__ wb,
          const float* __restrict__ b1g, const float* __restrict__ b2g) {
    __shared__ __align__(16) short Z[2][64][512];   // 128 KB
    __shared__ __align__(16) short A2[32][256];     // 16 KB
    __shared__ float wtr[48], wti[48];
    __shared__ float twr[64], twi[64];

    const int tid = threadIdx.x;
    const int s1  = blockIdx.x & 63;
    const size_t tbase = (size_t)blockIdx.x * 32768;
    char* Zb = (char*)Z;

    if (tid < 48) {
        float s_, c_;
        sincosf(TWO_PI * (float)tid / 64.0f, &s_, &c_);
        wtr[tid] = c_; wti[tid] = -s_;
    } else if (tid >= 64 && tid < 128) {
        const int n2 = tid - 64;
        float s_, c_;
        sincosf((TWO_PI / 4096.0f) * (float)(n2 * bitrev6(s1)), &s_, &c_);
        twr[n2] = c_; twi[n2] = s_;
    }

    // ---- P0: coalesced load of both planes into swizzled Z
#pragma unroll
    for (int i = 0; i < 16; ++i) {
        const int c = tid + i * 512;             // chunk of 8 bf16
        const int p = c >> 12;
        const int slot = (c >> 6) & 63;
        const int k8 = c & 63;
        const short* src = p ? zim : zre;
        const bf16x8 v = *(const bf16x8*)(src + tbase + slot * 512 + k8 * 8);
        *(bf16x8*)(Zb + p * 65536 + slot * 1024 + ((k8 * 16) ^ ((slot & 7) << 4))) = v;
    }
    __syncthreads();

    // ---- P1: forward FFT per channel column (thread = ch)
    {
        const int cb = tid * 2;
        float cr[64], ci[64];
#pragma unroll
        for (int s = 0; s < 64; ++s) {
            const int off = s * 1024 + (cb ^ ((s & 7) << 4));
            cr[s] = bf2f(*(const short*)(Zb + off));
            ci[s] = bf2f(*(const short*)(Zb + 65536 + off));
        }
        fft64_regs_fwd(cr, ci, wtr, wti);
#pragma unroll
        for (int s = 0; s < 64; ++s) {
            const int off = s * 1024 + (cb ^ ((s & 7) << 4));
            *(short*)(Zb + off) = f2bf(cr[s]);
            *(short*)(Zb + 65536 + off) = f2bf(ci[s]);
        }
    }
    __syncthreads();

    // ---- P2: forward fft4 across blocks + 1/128, in place
    {
        const int chp = tid & 127;
#pragma unroll
        for (int k = 0; k < 16; ++k) {
            const int slot = (tid >> 7) + k * 4;
            const int swz = (slot & 7) << 4;
            const int base = slot * 1024;
            float r[4], m[4];
#pragma unroll
            for (int q = 0; q < 4; ++q) {
                const int off = base + ((q * 256 + chp * 2) ^ swz);
                r[q] = bf2f(*(const short*)(Zb + off));
                m[q] = bf2f(*(const short*)(Zb + 65536 + off));
            }
            const float sc = 1.0f / 128.0f;
            float yr[4], yi[4];
            yr[0] = (r[0] + r[1] + r[2] + r[3]) * sc;  yi[0] = (m[0] + m[1] + m[2] + m[3]) * sc;
            yr[1] = (r[0] + m[1] - r[2] - m[3]) * sc;  yi[1] = (m[0] - r[1] - m[2] + r[3]) * sc;
            yr[2] = (r[0] - r[1] + r[2] - r[3]) * sc;  yi[2] = (m[0] - m[1] + m[2] - m[3]) * sc;
            yr[3] = (r[0] - m[1] - r[2] + m[3]) * sc;  yi[3] = (m[0] + r[1] - m[2] - r[3]) * sc;
#pragma unroll
            for (int q = 0; q < 4; ++q) {
                const int off = base + ((q * 256 + chp * 2) ^ swz);
                *(short*)(Zb + off) = f2bf(yr[q]);
                *(short*)(Zb + 65536 + off) = f2bf(yi[q]);
            }
        }
    }
    __syncthreads();

    // ---- P3: MLP (2 layers) per block, in 32-slot halves
    {
        const int wave = tid >> 6;
        const int lane = tid & 63;
        const int lrow = lane & 15;
        const int lk   = lane >> 4;

        for (int bq = 0; bq < 4; ++bq) {
            bf16x8 Bf1[2][8], Bf2[2][8];
#pragma unroll
            for (int nt = 0; nt < 2; ++nt) {
                const int n = wave * 32 + nt * 16 + lrow;
                const size_t wo = (size_t)(bq * 256 + n) * 256 + lk * 8;
#pragma unroll
                for (int ks = 0; ks < 8; ++ks) {
                    Bf1[nt][ks] = *(const bf16x8*)(wb + wo + ks * 32);
                    Bf2[nt][ks] = *(const bf16x8*)(wb + 262144 + wo + ks * 32);
                }
            }
            float bv1[2], bv2[2];
#pragma unroll
            for (int nt = 0; nt < 2; ++nt) {
                const int n = wave * 32 + nt * 16 + lrow;
                const int bi = (n < 128) ? (bq * 128 + n) : (512 + bq * 128 + (n - 128));
                bv1[nt] = b1g[bi];
                bv2[nt] = b2g[bi];
            }

            for (int h = 0; h < 2; ++h) {
                // layer 1: A from Z
                f32x4 acc[2][2];
#pragma unroll
                for (int mt = 0; mt < 2; ++mt)
#pragma unroll
                    for (int nt = 0; nt < 2; ++nt)
                        acc[mt][nt] = (f32x4){0.f, 0.f, 0.f, 0.f};
#pragma unroll
                for (int ks = 0; ks < 8; ++ks) {
                    bf16x8 af[2];
#pragma unroll
                    for (int mt = 0; mt < 2; ++mt) {
                        const int slot = h * 32 + mt * 16 + lrow;
                        const int kk = ks * 32 + lk * 8;
                        const int off = (kk >> 7) * 65536 + slot * 1024 +
                            ((bq * 256 + (kk & 127) * 2) ^ ((slot & 7) << 4));
                        af[mt] = *(const bf16x8*)(Zb + off);
                    }
#pragma unroll
                    for (int mt = 0; mt < 2; ++mt)
#pragma unroll
                        for (int nt = 0; nt < 2; ++nt)
                            acc[mt][nt] = __builtin_amdgcn_mfma_f32_16x16x32_bf16(
                                af[mt], Bf1[nt][ks], acc[mt][nt], 0, 0, 0);
                }
                // relu + bias -> A2
#pragma unroll
                for (int nt = 0; nt < 2; ++nt) {
                    const int n = wave * 32 + nt * 16 + lrow;
#pragma unroll
                    for (int mt = 0; mt < 2; ++mt)
#pragma unroll
                        for (int r = 0; r < 4; ++r) {
                            const int row = mt * 16 + lk * 4 + r;
                            const float v = fmaxf(acc[mt][nt][r] + bv1[nt], 0.0f);
                            const int off = row * 512 + ((n * 2) ^ ((row & 7) << 4));
                            *(short*)((char*)A2 + off) = f2bf(v);
                        }
                }
                __syncthreads();

                // layer 2: A from A2
#pragma unroll
                for (int mt = 0; mt < 2; ++mt)
#pragma unroll
                    for (int nt = 0; nt < 2; ++nt)
                        acc[mt][nt] = (f32x4){0.f, 0.f, 0.f, 0.f};
#pragma unroll
                for (int ks = 0; ks < 8; ++ks) {
                    bf16x8 af[2];
#pragma unroll
                    for (int mt = 0; mt < 2; ++mt) {
                        const int row = mt * 16 + lrow;
                        const int kk = ks * 32 + lk * 8;
                        const int off = row * 512 + ((kk * 2) ^ ((row & 7) << 4));
                        af[mt] = *(const bf16x8*)((const char*)A2 + off);
                    }
#pragma unroll
                    for (int mt = 0; mt < 2; ++mt)
#pragma unroll
                        for (int nt = 0; nt < 2; ++nt)
                            acc[mt][nt] = __builtin_amdgcn_mfma_f32_16x16x32_bf16(
                                af[mt], Bf2[nt][ks], acc[mt][nt], 0, 0, 0);
                }
                // softshrink + bias -> Z
#pragma unroll
                for (int nt = 0; nt < 2; ++nt) {
                    const int n = wave * 32 + nt * 16 + lrow;
                    const int p = n >> 7;
                    const int chb = bq * 256 + (n & 127) * 2;
#pragma unroll
                    for (int mt = 0; mt < 2; ++mt)
#pragma unroll
                        for (int r = 0; r < 4; ++r) {
                            const int slot = h * 32 + mt * 16 + lk * 4 + r;
                            float v = acc[mt][nt][r] + bv2[nt];
                            v = (v > 0.01f) ? v - 0.01f : ((v < -0.01f) ? v + 0.01f : 0.0f);
                            const int off = p * 65536 + slot * 1024 +
                                            (chb ^ ((slot & 7) << 4));
                            *(short*)(Zb + off) = f2bf(v);
                        }
                }
                __syncthreads();
            }
        }
    }

    // ---- P5a: inverse fft4 across blocks + 1/128, in place
    {
        const int chp = tid & 127;
#pragma unroll
        for (int k = 0; k < 16; ++k) {
            const int slot = (tid >> 7) + k * 4;
            const int swz = (slot & 7) << 4;
            const int base = slot * 1024;
            float r[4], m[4];
#pragma unroll
            for (int q = 0; q < 4; ++q) {
                const int off = base + ((q * 256 + chp * 2) ^ swz);
                r[q] = bf2f(*(const short*)(Zb + off));
                m[q] = bf2f(*(const short*)(Zb + 65536 + off));
            }
            const float sc = 1.0f / 128.0f;
            float yr[4], yi[4];
            yr[0] = (r[0] + r[1] + r[2] + r[3]) * sc;  yi[0] = (m[0] + m[1] + m[2] + m[3]) * sc;
            yr[1] = (r[0] - m[1] - r[2] + m[3]) * sc;  yi[1] = (m[0] + r[1] - m[2] - r[3]) * sc;
            yr[2] = (r[0] - r[1] + r[2] - r[3]) * sc;  yi[2] = (m[0] - m[1] + m[2] - m[3]) * sc;
            yr[3] = (r[0] + m[1] - r[2] - m[3]) * sc;  yi[3] = (m[0] - r[1] - m[2] - (-r[3])) * sc;
#pragma unroll
            for (int q = 0; q < 4; ++q) {
                const int off = base + ((q * 256 + chp * 2) ^ swz);
                *(short*)(Zb + off) = f2bf(yr[q]);
                *(short*)(Zb + 65536 + off) = f2bf(yi[q]);
            }
        }
    }
    __syncthreads();

    // ---- P5b: inverse FFT per column + output twiddle
    {
        const int cb = tid * 2;
        float cr[64], ci[64];
#pragma unroll
        for (int s = 0; s < 64; ++s) {
            const int off = s * 1024 + (cb ^ ((s & 7) << 4));
            cr[s] = bf2f(*(const short*)(Zb + off));
            ci[s] = bf2f(*(const short*)(Zb + 65536 + off));
        }
        fft64_regs_inv(cr, ci, wtr, wti);
#pragma unroll
        for (int s = 0; s < 64; ++s) {
            const float cs = twr[s], sn = twi[s];
            const float vr = cr[s] * cs - ci[s] * sn;
            const float vi = cr[s] * sn + ci[s] * cs;
            const int off = s * 1024 + (cb ^ ((s & 7) << 4));
            *(short*)(Zb + off) = f2bf(vr);
            *(short*)(Zb + 65536 + off) = f2bf(vi);
        }
    }
    __syncthreads();

    // ---- P6: coalesced store back to global
#pragma unroll
    for (int i = 0; i < 16; ++i) {
        const int c = tid + i * 512;
        const int p = c >> 12;
        const int slot = (c >> 6) & 63;
        const int k8 = c & 63;
        short* dst = (p ? zim : zre) + tbase + slot * 512 + k8 * 8;
        *(bf16x8*)dst = *(const bf16x8*)(Zb + p * 65536 + slot * 1024 +
                                         ((k8 * 16) ^ ((slot & 7) << 4)));
    }
}

extern "C" void kernel_launch(void* const* d_in, const int* in_sizes, int n_in,
                              void* d_out, int out_size, void* d_ws, size_t ws_size,
                              hipStream_t stream) {
    const float* x  = (const float*)d_in[0];
    const float* w1 = (const float*)d_in[1];
    const float* w2 = (const float*)d_in[2];
    const float* b1 = (const float*)d_in[3];
    const float* b2 = (const float*)d_in[4];

    float* out = (float*)d_out;
    short* zre = (short*)d_ws;            // bf16 real plane, 32 MiB
    short* zim = zre + 16777216;          // bf16 imag plane, 32 MiB
    short* wb  = (short*)d_out;           // 1 MiB W_big scratch inside d_out

    wprep<<<512, 256, 0, stream>>>(w1, w2, wb);

    fft_fwd_a<<<2048, 512, 0, stream>>>(x, zre, zim);

    mid_fused<<<512, 512, 0, stream>>>(zre, zim, wb, b1, b2);

    fft_inv_b<<<2048, 512, 0, stream>>>(zre, zim, out);
}

// Round 9
// 224.361 us; speedup vs baseline: 8.8619x; 1.1872x over previous
//
#include <hip/hip_runtime.h>
#include <math.h>

#define TWO_PI 6.283185307179586f

typedef __attribute__((ext_vector_type(8))) short bf16x8;
typedef __attribute__((ext_vector_type(4))) short bf16x4;
typedef __attribute__((ext_vector_type(4))) float f32x4;

__device__ __forceinline__ short f2bf(float f) {
    unsigned u = __float_as_uint(f);
    unsigned r = (u + 0x7FFFu + ((u >> 16) & 1u)) >> 16;   // RNE
    return (short)r;
}
__device__ __forceinline__ float bf2f(short s) {
    return __uint_as_float(((unsigned)(unsigned short)s) << 16);
}

// base-4 digit reversal of a 6-bit index (radix-4 FFT output order)
__device__ __forceinline__ int dr4(int s) {
    return ((s & 3) << 4) | (s & 12) | ((s >> 4) & 3);
}

__device__ __forceinline__ void cmulw(float& xr, float& xi, float wr, float wi) {
    const float tr = xr * wr - xi * wi;
    xi = xr * wi + xi * wr;
    xr = tr;
}

// ---------------------------------------------------------------------------
// LDS radix-4 64-point FFT across 128 channels, tile [64][128] fp32.
// 3 stages (vs 6 radix-2): half the LDS sweeps, half the barriers.
// DIF fwd: natural in -> base4-digit-reversed out, W^- twiddles (plain sum).
// DIT inv: digit-reversed in -> natural out, conj twiddles (plain sum).
// Math identical to the HW-verified register pair from round 8.
// c = tid&127 (channel), h = tid>>7 (0..3): 4 butterflies/stage/thread.
// wtr/wti: W64^m = (cos,-sin)(2pi m/64), m in [0,48).
// ---------------------------------------------------------------------------
__device__ __forceinline__ void fft64_dif4(float (*Lre)[128], float (*Lim)[128],
                                           const float* wtr, const float* wti,
                                           int c, int h) {
#pragma unroll
    for (int s = 0; s < 3; ++s) {
        const int q  = 16 >> (2 * s);
        const int tw = 1 << (2 * s);
        __syncthreads();
#pragma unroll
        for (int uu = 0; uu < 4; ++uu) {
            const int u = h * 4 + uu;
            const int j = u & (q - 1);
            const int g = (s == 0) ? 0 : (u >> (4 - 2 * s));
            const int i0 = g * (q << 2) + j;
            const int i1 = i0 + q, i2 = i1 + q, i3 = i2 + q;
            const float a0r = Lre[i0][c], a0i = Lim[i0][c];
            const float a1r = Lre[i1][c], a1i = Lim[i1][c];
            const float a2r = Lre[i2][c], a2i = Lim[i2][c];
            const float a3r = Lre[i3][c], a3i = Lim[i3][c];
            const float t0r = a0r + a2r, t0i = a0i + a2i;
            const float t2r = a0r - a2r, t2i = a0i - a2i;
            const float t1r = a1r + a3r, t1i = a1i + a3i;
            const float dr  = a1r - a3r, di  = a1i - a3i;
            const float t3r = di, t3i = -dr;                 // -i*(a1-a3)
            Lre[i0][c] = t0r + t1r;  Lim[i0][c] = t0i + t1i;
            float y1r = t2r + t3r, y1i = t2i + t3i;
            float y2r = t0r - t1r, y2i = t0i - t1i;
            float y3r = t2r - t3r, y3i = t2i - t3i;
            const int m = j * tw;
            if (m) {
                cmulw(y1r, y1i, wtr[m], wti[m]);
                cmulw(y2r, y2i, wtr[2 * m], wti[2 * m]);
                cmulw(y3r, y3i, wtr[3 * m], wti[3 * m]);
            }
            Lre[i1][c] = y1r; Lim[i1][c] = y1i;
            Lre[i2][c] = y2r; Lim[i2][c] = y2i;
            Lre[i3][c] = y3r; Lim[i3][c] = y3i;
        }
    }
    __syncthreads();
}

__device__ __forceinline__ void fft64_dit4(float (*Lre)[128], float (*Lim)[128],
                                           const float* wtr, const float* wti,
                                           int c, int h) {
#pragma unroll
    for (int s = 2; s >= 0; --s) {
        const int q  = 16 >> (2 * s);
        const int tw = 1 << (2 * s);
        __syncthreads();
#pragma unroll
        for (int uu = 0; uu < 4; ++uu) {
            const int u = h * 4 + uu;
            const int j = u & (q - 1);
            const int g = (s == 0) ? 0 : (u >> (4 - 2 * s));
            const int i0 = g * (q << 2) + j;
            const int i1 = i0 + q, i2 = i1 + q, i3 = i2 + q;
            float b1r = Lre[i1][c], b1i = Lim[i1][c];
            float b2r = Lre[i2][c], b2i = Lim[i2][c];
            float b3r = Lre[i3][c], b3i = Lim[i3][c];
            const int m = j * tw;
            if (m) {
                cmulw(b1r, b1i, wtr[m], -wti[m]);            // conj
                cmulw(b2r, b2i, wtr[2 * m], -wti[2 * m]);
                cmulw(b3r, b3i, wtr[3 * m], -wti[3 * m]);
            }
            const float a0r = Lre[i0][c], a0i = Lim[i0][c];
            const float u0r = a0r + b2r, u0i = a0i + b2i;
            const float u1r = a0r - b2r, u1i = a0i - b2i;
            const float u2r = b1r + b3r, u2i = b1i + b3i;
            const float dr  = b1r - b3r, di  = b1i - b3i;
            const float u3r = -di, u3i = dr;                 // +i*(b1-b3)
            Lre[i0][c] = u0r + u2r; Lim[i0][c] = u0i + u2i;
            Lre[i1][c] = u1r + u3r; Lim[i1][c] = u1i + u3i;
            Lre[i2][c] = u0r - u2r; Lim[i2][c] = u0i - u2i;
            Lre[i3][c] = u1r - u3r; Lim[i3][c] = u1i - u3i;
        }
    }
    __syncthreads();
}

#define DECODE_BCT() \
    const int b  = blockIdx.x >> 8; \
    const int dg = (blockIdx.x >> 2) & 63; \
    const int ct = blockIdx.x & 3;

#define GADDR(slot, blk, f4) \
    (((size_t)(b * 4096 + (slot)) * 512) + (size_t)((blk) * 128 + ct * 32 + (f4) * 4))

#define GADDR8(slot, blk, e8) \
    (((size_t)(b * 4096 + (slot)) * 512) + (size_t)((blk) * 128 + ct * 32 + (e8) * 8))

#define SETUP_TABLE48() \
    if (tid < 48) { \
        float s_, c_; \
        sincosf(TWO_PI * (float)tid / 64.0f, &s_, &c_); \
        wre[tid] = c_; wim[tid] = -s_; \
    }

// ---- forward pass A: FFT over n1 (slots 64*n1+dg), twiddle, x fp32 -> z bf16
extern "C" __global__ void __launch_bounds__(512)
fft_fwd_a(const float* __restrict__ x, short* __restrict__ zre, short* __restrict__ zim) {
    __shared__ __align__(16) float Lre[64][128];
    __shared__ __align__(16) float Lim[64][128];
    __shared__ float wre[48], wim[48];
    __shared__ float twr[64], twi[64];
    const int tid = threadIdx.x;
    SETUP_TABLE48();
    DECODE_BCT();   // dg = n2
    if (tid >= 64 && tid < 128) {
        const int s1 = tid - 64;
        float sn, cs;
        sincosf(-(TWO_PI / 4096.0f) * (float)(dg * dr4(s1)), &sn, &cs);
        twr[s1] = cs; twi[s1] = sn;
    }
    for (int idx = tid; idx < 2048; idx += 512) {
        const int n1 = idx >> 5, q = idx & 31, blk = q >> 3, f4 = q & 7;
        const int cl = blk * 32 + f4 * 4;
        const float4 v = *(const float4*)(x + GADDR(n1 * 64 + dg, blk, f4));
        *(float4*)&Lre[n1][cl] = v;
        float4 z; z.x = 0.f; z.y = 0.f; z.z = 0.f; z.w = 0.f;
        *(float4*)&Lim[n1][cl] = z;
    }
    fft64_dif4(Lre, Lim, wre, wim, tid & 127, tid >> 7);
    for (int idx = tid; idx < 2048; idx += 512) {
        const int s1 = idx >> 5, q = idx & 31, blk = q >> 3, f4 = q & 7;
        const int cl = blk * 32 + f4 * 4;
        const float cs = twr[s1], sn = twi[s1];
        const float4 vr = *(const float4*)&Lre[s1][cl];
        const float4 vi = *(const float4*)&Lim[s1][cl];
        bf16x4 pr, pi;
        pr[0] = f2bf(vr.x * cs - vi.x * sn);  pi[0] = f2bf(vr.x * sn + vi.x * cs);
        pr[1] = f2bf(vr.y * cs - vi.y * sn);  pi[1] = f2bf(vr.y * sn + vi.y * cs);
        pr[2] = f2bf(vr.z * cs - vi.z * sn);  pi[2] = f2bf(vr.z * sn + vi.z * cs);
        pr[3] = f2bf(vr.w * cs - vi.w * sn);  pi[3] = f2bf(vr.w * sn + vi.w * cs);
        const size_t g = GADDR(s1 * 64 + dg, blk, f4);
        *(bf16x4*)(zre + g) = pr;
        *(bf16x4*)(zim + g) = pi;
    }
}

// ---- forward pass B: FFT over n2 (contiguous slots) + fused fft4_fwd (x1/128)
extern "C" __global__ void __launch_bounds__(512)
fft_fwd_b(short* __restrict__ zre, short* __restrict__ zim) {
    __shared__ __align__(16) float Lre[64][128];
    __shared__ __align__(16) float Lim[64][128];
    __shared__ float wre[48], wim[48];
    const int tid = threadIdx.x;
    SETUP_TABLE48();
    DECODE_BCT();   // dg = s1
    for (int idx = tid; idx < 1024; idx += 512) {
        const int n2 = idx >> 4, q = idx & 15, blk = q >> 2, e8 = q & 3;
        const int cl = blk * 32 + e8 * 8;
        const size_t g = GADDR8(dg * 64 + n2, blk, e8);
        const bf16x8 vr = *(const bf16x8*)(zre + g);
        const bf16x8 vi = *(const bf16x8*)(zim + g);
        float4 a, bq;
        a.x = bf2f(vr[0]); a.y = bf2f(vr[1]); a.z = bf2f(vr[2]); a.w = bf2f(vr[3]);
        bq.x = bf2f(vr[4]); bq.y = bf2f(vr[5]); bq.z = bf2f(vr[6]); bq.w = bf2f(vr[7]);
        *(float4*)&Lre[n2][cl] = a;
        *(float4*)&Lre[n2][cl + 4] = bq;
        a.x = bf2f(vi[0]); a.y = bf2f(vi[1]); a.z = bf2f(vi[2]); a.w = bf2f(vi[3]);
        bq.x = bf2f(vi[4]); bq.y = bf2f(vi[5]); bq.z = bf2f(vi[6]); bq.w = bf2f(vi[7]);
        *(float4*)&Lim[n2][cl] = a;
        *(float4*)&Lim[n2][cl + 4] = bq;
    }
    fft64_dif4(Lre, Lim, wre, wim, tid & 127, tid >> 7);
    for (int idx = tid; idx < 2048; idx += 512) {
        const int s = idx >> 5, dl = idx & 31;
        const float r0 = Lre[s][dl], r1 = Lre[s][dl + 32], r2 = Lre[s][dl + 64], r3 = Lre[s][dl + 96];
        const float m0 = Lim[s][dl], m1 = Lim[s][dl + 32], m2 = Lim[s][dl + 64], m3 = Lim[s][dl + 96];
        const float sc = 1.0f / 128.0f;
        Lre[s][dl]      = (r0 + r1 + r2 + r3) * sc;  Lim[s][dl]      = (m0 + m1 + m2 + m3) * sc;
        Lre[s][dl + 32] = (r0 + m1 - r2 - m3) * sc;  Lim[s][dl + 32] = (m0 - r1 - m2 + r3) * sc;
        Lre[s][dl + 64] = (r0 - r1 + r2 - r3) * sc;  Lim[s][dl + 64] = (m0 - m1 + m2 - m3) * sc;
        Lre[s][dl + 96] = (r0 - m1 - r2 + m3) * sc;  Lim[s][dl + 96] = (m0 + r1 - m2 - r3) * sc;
    }
    __syncthreads();
    for (int idx = tid; idx < 1024; idx += 512) {
        const int s2 = idx >> 4, q = idx & 15, blk = q >> 2, e8 = q & 3;
        const int cl = blk * 32 + e8 * 8;
        bf16x8 pr, pi;
#pragma unroll
        for (int i = 0; i < 8; ++i) {
            pr[i] = f2bf(Lre[s2][cl + i]);
            pi[i] = f2bf(Lim[s2][cl + i]);
        }
        const size_t g = GADDR8(dg * 64 + s2, blk, e8);
        *(bf16x8*)(zre + g) = pr;
        *(bf16x8*)(zim + g) = pi;
    }
}

// ---- inverse pass A: fused fft4_inv (x1/128), inverse FFT over k2, twiddle
extern "C" __global__ void __launch_bounds__(512)
fft_inv_a(short* __restrict__ zre, short* __restrict__ zim) {
    __shared__ __align__(16) float Lre[64][128];
    __shared__ __align__(16) float Lim[64][128];
    __shared__ float wre[48], wim[48];
    __shared__ float twr[64], twi[64];
    const int tid = threadIdx.x;
    SETUP_TABLE48();
    DECODE_BCT();   // dg = s1
    if (tid >= 64 && tid < 128) {
        const int n2 = tid - 64;
        float sn, cs;
        sincosf((TWO_PI / 4096.0f) * (float)(n2 * dr4(dg)), &sn, &cs);
        twr[n2] = cs; twi[n2] = sn;
    }
    for (int idx = tid; idx < 1024; idx += 512) {
        const int s2 = idx >> 4, q = idx & 15, blk = q >> 2, e8 = q & 3;
        const int cl = blk * 32 + e8 * 8;
        const size_t g = GADDR8(dg * 64 + s2, blk, e8);
        const bf16x8 vr = *(const bf16x8*)(zre + g);
        const bf16x8 vi = *(const bf16x8*)(zim + g);
        float4 a, bq;
        a.x = bf2f(vr[0]); a.y = bf2f(vr[1]); a.z = bf2f(vr[2]); a.w = bf2f(vr[3]);
        bq.x = bf2f(vr[4]); bq.y = bf2f(vr[5]); bq.z = bf2f(vr[6]); bq.w = bf2f(vr[7]);
        *(float4*)&Lre[s2][cl] = a;
        *(float4*)&Lre[s2][cl + 4] = bq;
        a.x = bf2f(vi[0]); a.y = bf2f(vi[1]); a.z = bf2f(vi[2]); a.w = bf2f(vi[3]);
        bq.x = bf2f(vi[4]); bq.y = bf2f(vi[5]); bq.z = bf2f(vi[6]); bq.w = bf2f(vi[7]);
        *(float4*)&Lim[s2][cl] = a;
        *(float4*)&Lim[s2][cl + 4] = bq;
    }
    __syncthreads();
    for (int idx = tid; idx < 2048; idx += 512) {
        const int s = idx >> 5, dl = idx & 31;
        const float r0 = Lre[s][dl], r1 = Lre[s][dl + 32], r2 = Lre[s][dl + 64], r3 = Lre[s][dl + 96];
        const float m0 = Lim[s][dl], m1 = Lim[s][dl + 32], m2 = Lim[s][dl + 64], m3 = Lim[s][dl + 96];
        const float sc = 1.0f / 128.0f;
        Lre[s][dl]      = (r0 + r1 + r2 + r3) * sc;  Lim[s][dl]      = (m0 + m1 + m2 + m3) * sc;
        Lre[s][dl + 32] = (r0 - m1 - r2 + m3) * sc;  Lim[s][dl + 32] = (m0 + r1 - m2 - r3) * sc;
        Lre[s][dl + 64] = (r0 - r1 + r2 - r3) * sc;  Lim[s][dl + 64] = (m0 - m1 + m2 - m3) * sc;
        Lre[s][dl + 96] = (r0 + m1 - r2 - m3) * sc;  Lim[s][dl + 96] = (m0 - r1 - m2 + r3) * sc;
    }
    fft64_dit4(Lre, Lim, wre, wim, tid & 127, tid >> 7);
    for (int idx = tid; idx < 2048; idx += 512) {
        const int n2 = idx >> 5, q = idx & 31, blk = q >> 3, f4 = q & 7;
        const int cl = blk * 32 + f4 * 4;
        const float cs = twr[n2], sn = twi[n2];
        const float4 vr = *(const float4*)&Lre[n2][cl];
        const float4 vi = *(const float4*)&Lim[n2][cl];
        bf16x4 pr, pi;
        pr[0] = f2bf(vr.x * cs - vi.x * sn);  pi[0] = f2bf(vr.x * sn + vi.x * cs);
        pr[1] = f2bf(vr.y * cs - vi.y * sn);  pi[1] = f2bf(vr.y * sn + vi.y * cs);
        pr[2] = f2bf(vr.z * cs - vi.z * sn);  pi[2] = f2bf(vr.z * sn + vi.z * cs);
        pr[3] = f2bf(vr.w * cs - vi.w * sn);  pi[3] = f2bf(vr.w * sn + vi.w * cs);
        const size_t g = GADDR(dg * 64 + n2, blk, f4);
        *(bf16x4*)(zre + g) = pr;
        *(bf16x4*)(zim + g) = pi;
    }
}

// ---- inverse pass B: inverse FFT over k1, write REAL fp32 into d_out
extern "C" __global__ void __launch_bounds__(512)
fft_inv_b(const short* __restrict__ zre, const short* __restrict__ zim,
          float* __restrict__ out) {
    __shared__ __align__(16) float Lre[64][128];
    __shared__ __align__(16) float Lim[64][128];
    __shared__ float wre[48], wim[48];
    const int tid = threadIdx.x;
    SETUP_TABLE48();
    DECODE_BCT();   // dg = n2
    for (int idx = tid; idx < 1024; idx += 512) {
        const int s1 = idx >> 4, q = idx & 15, blk = q >> 2, e8 = q & 3;
        const int cl = blk * 32 + e8 * 8;
        const size_t g = GADDR8(s1 * 64 + dg, blk, e8);
        const bf16x8 vr = *(const bf16x8*)(zre + g);
        const bf16x8 vi = *(const bf16x8*)(zim + g);
        float4 a, bq;
        a.x = bf2f(vr[0]); a.y = bf2f(vr[1]); a.z = bf2f(vr[2]); a.w = bf2f(vr[3]);
        bq.x = bf2f(vr[4]); bq.y = bf2f(vr[5]); bq.z = bf2f(vr[6]); bq.w = bf2f(vr[7]);
        *(float4*)&Lre[s1][cl] = a;
        *(float4*)&Lre[s1][cl + 4] = bq;
        a.x = bf2f(vi[0]); a.y = bf2f(vi[1]); a.z = bf2f(vi[2]); a.w = bf2f(vi[3]);
        bq.x = bf2f(vi[4]); bq.y = bf2f(vi[5]); bq.z = bf2f(vi[6]); bq.w = bf2f(vi[7]);
        *(float4*)&Lim[s1][cl] = a;
        *(float4*)&Lim[s1][cl + 4] = bq;
    }
    fft64_dit4(Lre, Lim, wre, wim, tid & 127, tid >> 7);
    for (int idx = tid; idx < 2048; idx += 512) {
        const int n1 = idx >> 5, q = idx & 31, blk = q >> 3, f4 = q & 7;
        const int cl = blk * 32 + f4 * 4;
        *(float4*)(out + GADDR(n1 * 64 + dg, blk, f4)) = *(const float4*)&Lre[n1][cl];
    }
}

// ---------------------------------------------------------------------------
// Weight prep: fold complex 2x2 into W_big bf16 [L][blk][n][k], in d_out.
// ---------------------------------------------------------------------------
extern "C" __global__ void __launch_bounds__(256)
wprep(const float* __restrict__ w1, const float* __restrict__ w2,
      short* __restrict__ wb) {
    const int i4  = blockIdx.x * 256 + threadIdx.x;
    const int k0  = (i4 & 63) * 4;
    const int n   = (i4 >> 6) & 255;
    const int blk = (i4 >> 14) & 3;
    const int L   = i4 >> 16;
    const float* w = L ? w2 : w1;
    bf16x4 pv;
#pragma unroll
    for (int j = 0; j < 4; ++j) {
        const int k = k0 + j;
        float v;
        if (k < 128) {
            v = (n < 128) ? w[blk * 16384 + k * 128 + n]
                          : w[65536 + blk * 16384 + k * 128 + (n - 128)];
        } else {
            v = (n < 128) ? -w[65536 + blk * 16384 + (k - 128) * 128 + n]
                          :  w[blk * 16384 + (k - 128) * 128 + (n - 128)];
        }
        pv[j] = f2bf(v);
    }
    *(bf16x4*)(wb + (size_t)i4 * 4) = pv;
}

// ---------------------------------------------------------------------------
// MFMA block-diagonal complex MLP layer over bf16 planes, in place.
// global_load_lds staging (swizzle on global source addr), double-buffered.
// ---------------------------------------------------------------------------
#define MITER 4

__device__ __forceinline__ void stage_tile(const short* __restrict__ zre,
                                           const short* __restrict__ zim,
                                           char* Abuf, int rowbase, int blk,
                                           int wave, int lane) {
#pragma unroll
    for (int it = 0; it < 4; ++it) {
        const int chunk = wave * 256 + it * 64 + lane;   // 16B chunk id, 0..2047
        const int row   = chunk >> 5;
        const unsigned kbyte = ((unsigned)((chunk & 31) << 4)) ^ ((unsigned)((row & 7) << 4));
        const int k0 = (int)(kbyte >> 1);                // element k, multiple of 8
        const short* src = (k0 < 128) ? zre : zim;
        const size_t g = (size_t)(rowbase + row) * 512 + blk * 128 + (k0 & 127);
        unsigned* lp = (unsigned*)(Abuf + (wave * 4096 + it * 1024));  // wave-uniform
        __builtin_amdgcn_global_load_lds((const unsigned*)(src + g), lp, 16, 0, 0);
    }
}

template<int LAYER>
__global__ void __launch_bounds__(512)
mlp_mfma(short* __restrict__ zre, short* __restrict__ zim,
         const short* __restrict__ wb, const float* __restrict__ bias) {
    __shared__ __align__(16) char As[2][64 * 256 * 2];   // 2 x 32 KB bf16, swizzled

    const int blk  = blockIdx.y;
    const int tid  = threadIdx.x;
    const int wave = tid >> 6;
    const int lane = tid & 63;
    const int lrow = lane & 15;
    const int lk   = lane >> 4;

    bf16x8 Bf[2][8];
#pragma unroll
    for (int nt = 0; nt < 2; ++nt) {
        const int n = wave * 32 + nt * 16 + lrow;
#pragma unroll
        for (int ks = 0; ks < 8; ++ks) {
            Bf[nt][ks] = *(const bf16x8*)(wb + ((size_t)(blk * 256 + n) * 256 + ks * 32 + lk * 8));
        }
    }

    float bv[2];
#pragma unroll
    for (int nt = 0; nt < 2; ++nt) {
        const int n = wave * 32 + nt * 16 + lrow;
        bv[nt] = (n < 128) ? bias[blk * 128 + n] : bias[512 + blk * 128 + (n - 128)];
    }

    stage_tile(zre, zim, As[0], blockIdx.x * MITER * 64, blk, wave, lane);

    for (int t = 0; t < MITER; ++t) {
        __syncthreads();

        if (t + 1 < MITER)
            stage_tile(zre, zim, As[(t + 1) & 1],
                       (blockIdx.x * MITER + t + 1) * 64, blk, wave, lane);

        const char* Ab = As[t & 1];
        const int rowbase = (blockIdx.x * MITER + t) * 64;

        f32x4 acc[4][2];
#pragma unroll
        for (int mt = 0; mt < 4; ++mt)
#pragma unroll
            for (int nt = 0; nt < 2; ++nt)
                acc[mt][nt] = (f32x4){0.f, 0.f, 0.f, 0.f};

#pragma unroll
        for (int ks = 0; ks < 8; ++ks) {
            bf16x8 af[4];
#pragma unroll
            for (int mt = 0; mt < 4; ++mt) {
                const int row = mt * 16 + lrow;
                const int k0  = ks * 32 + lk * 8;
                const unsigned byteoff =
                    ((unsigned)(row * 512 + k0 * 2)) ^ ((unsigned)((row & 7) << 4));
                af[mt] = *(const bf16x8*)(Ab + byteoff);
            }
#pragma unroll
            for (int mt = 0; mt < 4; ++mt)
#pragma unroll
                for (int nt = 0; nt < 2; ++nt)
                    acc[mt][nt] = __builtin_amdgcn_mfma_f32_16x16x32_bf16(
                        af[mt], Bf[nt][ks], acc[mt][nt], 0, 0, 0);
        }

#pragma unroll
        for (int nt = 0; nt < 2; ++nt) {
            const int n = wave * 32 + nt * 16 + lrow;
            short* dst = (n < 128) ? zre : zim;
            const int col = blk * 128 + (n & 127);
#pragma unroll
            for (int mt = 0; mt < 4; ++mt) {
#pragma unroll
                for (int r = 0; r < 4; ++r) {
                    const int row = rowbase + mt * 16 + lk * 4 + r;
                    float v = acc[mt][nt][r] + bv[nt];
                    if (LAYER == 1) {
                        v = fmaxf(v, 0.0f);
                    } else {
                        v = (v > 0.01f) ? v - 0.01f : ((v < -0.01f) ? v + 0.01f : 0.0f);
                    }
                    dst[(size_t)row * 512 + col] = f2bf(v);
                }
            }
        }
    }
}

extern "C" void kernel_launch(void* const* d_in, const int* in_sizes, int n_in,
                              void* d_out, int out_size, void* d_ws, size_t ws_size,
                              hipStream_t stream) {
    const float* x  = (const float*)d_in[0];
    const float* w1 = (const float*)d_in[1];
    const float* w2 = (const float*)d_in[2];
    const float* b1 = (const float*)d_in[3];
    const float* b2 = (const float*)d_in[4];

    float* out = (float*)d_out;
    short* zre = (short*)d_ws;            // bf16 real plane, 32 MiB
    short* zim = zre + 16777216;          // bf16 imag plane, 32 MiB
    short* wb  = (short*)d_out;           // 1 MiB W_big scratch inside d_out
    const size_t WB_L = 4ull * 256 * 256;

    wprep<<<512, 256, 0, stream>>>(w1, w2, wb);

    // forward FFT2 (ortho), radix-4 four-step; fft4+scale fused into pass B
    fft_fwd_a<<<2048, 512, 0, stream>>>(x, zre, zim);
    fft_fwd_b<<<2048, 512, 0, stream>>>(zre, zim);

    // block-diagonal complex MLP via MFMA, one dispatch per layer, in place
    mlp_mfma<1><<<dim3(32768 / (64 * MITER), 4), 512, 0, stream>>>(zre, zim, wb, b1);
    mlp_mfma<2><<<dim3(32768 / (64 * MITER), 4), 512, 0, stream>>>(zre, zim, wb + WB_L, b2);

    // inverse FFT2 (ortho), radix-4; fft4_inv+scale fused into pass A
    fft_inv_a<<<2048, 512, 0, stream>>>(zre, zim);
    fft_inv_b<<<2048, 512, 0, stream>>>(zre, zim, out);
}